// Round 1
// baseline (6715.125 us; speedup 1.0000x reference)
//
#include <hip/hip_runtime.h>

// MyTransformer: 6-layer encoder + 6-layer decoder, S=1024, D=512, H=8(x64), FF=2048, fp32.
// Round 0: correctness-first fp32 pipeline. Tiled SIMT GEMM (64x64 tile, 4x4/thread),
// wave-per-row softmax / LN / L2-norm. All launches on `stream`, graph-capture safe.

#define S_TOK 1024
#define D_MOD 512
#define NHEAD 8
#define HDIM  64
#define NLAY  6
#define DFF   2048

// ----------------------------- GEMM -----------------------------------------
// C[m][n] = alpha * sum_k A[m][k] * B(k,n) + bias[n]   (optional relu)
// B(k,n) = TRANS_B ? B[n*ldb+k] : B[k*ldb+n]
// Grid: (N/64, M/64, batch). All of M,N multiples of 64; K multiple of 16.
template<bool TRANS_B, bool RELU>
__global__ __launch_bounds__(256)
void gemm_kern(const float* __restrict__ A, int lda, long sA,
               const float* __restrict__ B, int ldb, long sB,
               const float* __restrict__ bias,
               float* __restrict__ C, int ldc, long sC,
               int K, float alpha)
{
    __shared__ float As[16][65];   // As[k][m], +1 pad
    __shared__ float Bs[16][65];   // Bs[k][n]
    const int bz = blockIdx.z;
    A += (long)bz * sA;  B += (long)bz * sB;  C += (long)bz * sC;
    const int m0 = blockIdx.y * 64;
    const int n0 = blockIdx.x * 64;
    const int tid = threadIdx.x;
    const int tx = tid & 15, ty = tid >> 4;
    float acc[4][4] = {};

    for (int k0 = 0; k0 < K; k0 += 16) {
        {   // A tile: 64 rows x 16 k, one float4 per thread
            const int row = tid >> 2;
            const int kq  = (tid & 3) << 2;
            const float4 av = *reinterpret_cast<const float4*>(A + (long)(m0 + row) * lda + k0 + kq);
            As[kq + 0][row] = av.x;  As[kq + 1][row] = av.y;
            As[kq + 2][row] = av.z;  As[kq + 3][row] = av.w;
        }
        if (TRANS_B) {
            const int row = tid >> 2;          // n index
            const int kq  = (tid & 3) << 2;
            const float4 bv = *reinterpret_cast<const float4*>(B + (long)(n0 + row) * ldb + k0 + kq);
            Bs[kq + 0][row] = bv.x;  Bs[kq + 1][row] = bv.y;
            Bs[kq + 2][row] = bv.z;  Bs[kq + 3][row] = bv.w;
        } else {
            const int kk = tid >> 4;           // k index 0..15
            const int nq = (tid & 15) << 2;    // n offset
            const float4 bv = *reinterpret_cast<const float4*>(B + (long)(k0 + kk) * ldb + n0 + nq);
            Bs[kk][nq + 0] = bv.x;  Bs[kk][nq + 1] = bv.y;
            Bs[kk][nq + 2] = bv.z;  Bs[kk][nq + 3] = bv.w;
        }
        __syncthreads();
        #pragma unroll
        for (int kk = 0; kk < 16; ++kk) {
            float a[4], b[4];
            #pragma unroll
            for (int i = 0; i < 4; ++i) a[i] = As[kk][(ty << 2) + i];
            #pragma unroll
            for (int j = 0; j < 4; ++j) b[j] = Bs[kk][(tx << 2) + j];
            #pragma unroll
            for (int i = 0; i < 4; ++i)
                #pragma unroll
                for (int j = 0; j < 4; ++j)
                    acc[i][j] = fmaf(a[i], b[j], acc[i][j]);
        }
        __syncthreads();
    }

    #pragma unroll
    for (int i = 0; i < 4; ++i) {
        const long m = m0 + (ty << 2) + i;
        #pragma unroll
        for (int j = 0; j < 4; ++j) {
            const int n = n0 + (tx << 2) + j;
            float v = acc[i][j] * alpha;
            if (bias) v += bias[n];
            if (RELU) v = fmaxf(v, 0.0f);
            C[m * ldc + n] = v;
        }
    }
}

// ------------------------- softmax over rows of 1024 -------------------------
__global__ __launch_bounds__(256)
void softmax_k(float* __restrict__ Sc)
{
    const int lane = threadIdx.x & 63;
    const int row  = (blockIdx.x << 2) + (threadIdx.x >> 6);
    float* p = Sc + (long)row * 1024;
    float v[16];
    float mx = -3.4e38f;
    #pragma unroll
    for (int i = 0; i < 16; ++i) { v[i] = p[lane + (i << 6)]; mx = fmaxf(mx, v[i]); }
    #pragma unroll
    for (int off = 32; off; off >>= 1) mx = fmaxf(mx, __shfl_xor(mx, off));
    float sum = 0.f;
    #pragma unroll
    for (int i = 0; i < 16; ++i) { v[i] = __expf(v[i] - mx); sum += v[i]; }
    #pragma unroll
    for (int off = 32; off; off >>= 1) sum += __shfl_xor(sum, off);
    const float inv = 1.0f / sum;
    #pragma unroll
    for (int i = 0; i < 16; ++i) p[lane + (i << 6)] = v[i] * inv;
}

// ---------------------- LayerNorm over rows of 512 ---------------------------
// out[row] = LN(x[row] + (a ? a[row] : 0)) * s + b.  One wave per row.
__global__ __launch_bounds__(256)
void ln_k(const float* __restrict__ x, const float* __restrict__ a,
          const float* __restrict__ s, const float* __restrict__ b,
          float* __restrict__ out)
{
    const int lane = threadIdx.x & 63;
    const int row  = (blockIdx.x << 2) + (threadIdx.x >> 6);
    const float* px = x + (long)row * 512;
    float v[8];
    float sum = 0.f;
    #pragma unroll
    for (int i = 0; i < 8; ++i) {
        v[i] = px[lane + (i << 6)];
        if (a) v[i] += a[(long)row * 512 + lane + (i << 6)];
        sum += v[i];
    }
    #pragma unroll
    for (int off = 32; off; off >>= 1) sum += __shfl_xor(sum, off);
    const float m = sum * (1.0f / 512.0f);
    float s2 = 0.f;
    #pragma unroll
    for (int i = 0; i < 8; ++i) { const float d = v[i] - m; s2 += d * d; }
    #pragma unroll
    for (int off = 32; off; off >>= 1) s2 += __shfl_xor(s2, off);
    const float inv = rsqrtf(s2 * (1.0f / 512.0f) + 1e-5f);
    #pragma unroll
    for (int i = 0; i < 8; ++i) {
        const int j = lane + (i << 6);
        out[(long)row * 512 + j] = (v[i] - m) * inv * s[j] + b[j];
    }
}

// ---------------------- L2 row-normalize (rows of 512) -----------------------
__global__ __launch_bounds__(256)
void l2norm_k(const float* __restrict__ x, float* __restrict__ out)
{
    const int lane = threadIdx.x & 63;
    const int row  = (blockIdx.x << 2) + (threadIdx.x >> 6);
    const float* px = x + (long)row * 512;
    float v[8];
    float s2 = 0.f;
    #pragma unroll
    for (int i = 0; i < 8; ++i) { v[i] = px[lane + (i << 6)]; s2 += v[i] * v[i]; }
    #pragma unroll
    for (int off = 32; off; off >>= 1) s2 += __shfl_xor(s2, off);
    const float inv = rsqrtf(s2);
    #pragma unroll
    for (int i = 0; i < 8; ++i) out[(long)row * 512 + lane + (i << 6)] = v[i] * inv;
}

// ------------------------------- copy x -> MEM, Y ----------------------------
__global__ __launch_bounds__(256)
void copy2_k(const float4* __restrict__ src, float4* __restrict__ a, float4* __restrict__ b)
{
    const int i = blockIdx.x * 256 + threadIdx.x;   // 131072 float4 total
    const float4 v = src[i];
    a[i] = v;  b[i] = v;
}

// ------------------------------ host-side helpers ----------------------------
static void gemm_launch(hipStream_t st, bool transB, bool relu,
                        const float* A, int lda, long sA,
                        const float* B, int ldb, long sB,
                        const float* bias, float* C, int ldc, long sC,
                        int M, int N, int K, float alpha, int batch)
{
    dim3 grid(N / 64, M / 64, batch);
    if (transB) {
        if (relu) gemm_kern<true, true ><<<grid, 256, 0, st>>>(A, lda, sA, B, ldb, sB, bias, C, ldc, sC, K, alpha);
        else      gemm_kern<true, false><<<grid, 256, 0, st>>>(A, lda, sA, B, ldb, sB, bias, C, ldc, sC, K, alpha);
    } else {
        gemm_kern<false, false><<<grid, 256, 0, st>>>(A, lda, sA, B, ldb, sB, bias, C, ldc, sC, K, alpha);
    }
}

// Full MHA block: qkv gemm(s) -> scores -> softmax -> AV -> out-proj (into PR).
static void run_attention(hipStream_t st, const float* q_in, const float* kv_in,
                          const float* wqkv, const float* bqkv,
                          const float* wo, const float* bo,
                          float* QKV, float* SC, float* AO, float* PR)
{
    if (q_in == kv_in) {
        gemm_launch(st, true, false, q_in, 512, 0, wqkv, 512, 0, bqkv,
                    QKV, 1536, 0, 1024, 1536, 512, 1.0f, 1);
    } else {
        gemm_launch(st, true, false, q_in, 512, 0, wqkv, 512, 0, bqkv,
                    QKV, 1536, 0, 1024, 512, 512, 1.0f, 1);
        gemm_launch(st, true, false, kv_in, 512, 0, wqkv + 512 * 512, 512, 0, bqkv + 512,
                    QKV + 512, 1536, 0, 1024, 1024, 512, 1.0f, 1);
    }
    // scores[h][q][k] = (1/8) q_h . k_h   (batched over 8 heads)
    gemm_launch(st, true, false, QKV, 1536, 64, QKV + 512, 1536, 64, nullptr,
                SC, 1024, 1024 * 1024, 1024, 1024, 64, 0.125f, 8);
    softmax_k<<<2048, 256, 0, st>>>(SC);
    // AO[q][h*64+d] = sum_k P[h][q][k] * V[k][h*64+d]
    gemm_launch(st, false, false, SC, 1024, 1024 * 1024, QKV + 1024, 1536, 64, nullptr,
                AO, 512, 64, 1024, 64, 1024, 1.0f, 8);
    // out projection
    gemm_launch(st, true, false, AO, 512, 0, wo, 512, 0, bo,
                PR, 512, 0, 1024, 512, 512, 1.0f, 1);
}

static void run_ffn(hipStream_t st, const float* in,
                    const float* w1, const float* b1,
                    const float* w2, const float* b2,
                    float* F1, float* F2)
{
    gemm_launch(st, true, true,  in, 512,  0, w1, 512,  0, b1, F1, 2048, 0, 1024, 2048, 512,  1.0f, 1);
    gemm_launch(st, true, false, F1, 2048, 0, w2, 2048, 0, b2, F2, 512,  0, 1024, 512,  2048, 1.0f, 1);
}

extern "C" void kernel_launch(void* const* d_in, const int* in_sizes, int n_in,
                              void* d_out, int out_size, void* d_ws, size_t ws_size,
                              hipStream_t stream)
{
    const float* x            = (const float*)d_in[0];
    const float* enc_qkv_w    = (const float*)d_in[1];
    const float* enc_qkv_b    = (const float*)d_in[2];
    const float* enc_out_w    = (const float*)d_in[3];
    const float* enc_out_b    = (const float*)d_in[4];
    const float* enc_ff1_w    = (const float*)d_in[5];
    const float* enc_ff1_b    = (const float*)d_in[6];
    const float* enc_ff2_w    = (const float*)d_in[7];
    const float* enc_ff2_b    = (const float*)d_in[8];
    const float* enc_ln1_s    = (const float*)d_in[9];
    const float* enc_ln1_b    = (const float*)d_in[10];
    const float* enc_ln2_s    = (const float*)d_in[11];
    const float* enc_ln2_b    = (const float*)d_in[12];
    const float* dec_sa_qkv_w = (const float*)d_in[13];
    const float* dec_sa_qkv_b = (const float*)d_in[14];
    const float* dec_sa_out_w = (const float*)d_in[15];
    const float* dec_sa_out_b = (const float*)d_in[16];
    const float* dec_ca_qkv_w = (const float*)d_in[17];
    const float* dec_ca_qkv_b = (const float*)d_in[18];
    const float* dec_ca_out_w = (const float*)d_in[19];
    const float* dec_ca_out_b = (const float*)d_in[20];
    const float* dec_ff1_w    = (const float*)d_in[21];
    const float* dec_ff1_b    = (const float*)d_in[22];
    const float* dec_ff2_w    = (const float*)d_in[23];
    const float* dec_ff2_b    = (const float*)d_in[24];
    const float* dec_ln1_s    = (const float*)d_in[25];
    const float* dec_ln1_b    = (const float*)d_in[26];
    const float* dec_ln2_s    = (const float*)d_in[27];
    const float* dec_ln2_b    = (const float*)d_in[28];
    const float* dec_ln3_s    = (const float*)d_in[29];
    const float* dec_ln3_b    = (const float*)d_in[30];
    const float* enc_norm_s   = (const float*)d_in[31];
    const float* enc_norm_b   = (const float*)d_in[32];
    const float* dec_norm_s   = (const float*)d_in[33];
    const float* dec_norm_b   = (const float*)d_in[34];

    // workspace layout (floats); total ~15.2M floats ~= 61 MB
    float* ws  = (float*)d_ws;
    float* MEM = ws;                       // 1024*512
    float* Y   = MEM + 1024 * 512;         // 1024*512
    float* QKV = Y   + 1024 * 512;         // 1024*1536
    float* SC  = QKV + 1024 * 1536;        // 8*1024*1024
    float* AO  = SC  + 8 * 1024 * 1024;    // 1024*512
    float* PR  = AO  + 1024 * 512;         // 1024*512
    float* F1  = PR  + 1024 * 512;         // 1024*2048
    float* F2  = F1  + 1024 * 2048;        // 1024*512
    float* NB  = F2  + 1024 * 512;         // 1024*512

    float* out_gram = (float*)d_out;                 // 1024*1024
    float* out_attn = out_gram + 1024 * 1024;        // 1024*512

    copy2_k<<<512, 256, 0, stream>>>((const float4*)x, (float4*)MEM, (float4*)Y);

    // ----------------------------- encoder ----------------------------------
    for (int i = 0; i < NLAY; ++i) {
        run_attention(stream, MEM, MEM,
                      enc_qkv_w + (long)i * 1536 * 512, enc_qkv_b + i * 1536,
                      enc_out_w + (long)i * 512 * 512,  enc_out_b + i * 512,
                      QKV, SC, AO, PR);
        ln_k<<<256, 256, 0, stream>>>(MEM, PR, enc_ln1_s + i * 512, enc_ln1_b + i * 512, MEM);
        run_ffn(stream, MEM,
                enc_ff1_w + (long)i * 2048 * 512, enc_ff1_b + i * 2048,
                enc_ff2_w + (long)i * 512 * 2048, enc_ff2_b + i * 512, F1, F2);
        ln_k<<<256, 256, 0, stream>>>(MEM, F2, enc_ln2_s + i * 512, enc_ln2_b + i * 512, MEM);
    }
    ln_k<<<256, 256, 0, stream>>>(MEM, nullptr, enc_norm_s, enc_norm_b, MEM);

    // ----------------------------- decoder ----------------------------------
    for (int i = 0; i < NLAY; ++i) {
        run_attention(stream, Y, Y,
                      dec_sa_qkv_w + (long)i * 1536 * 512, dec_sa_qkv_b + i * 1536,
                      dec_sa_out_w + (long)i * 512 * 512,  dec_sa_out_b + i * 512,
                      QKV, SC, AO, PR);
        ln_k<<<256, 256, 0, stream>>>(Y, PR, dec_ln1_s + i * 512, dec_ln1_b + i * 512, Y);

        run_attention(stream, Y, MEM,
                      dec_ca_qkv_w + (long)i * 1536 * 512, dec_ca_qkv_b + i * 1536,
                      dec_ca_out_w + (long)i * 512 * 512,  dec_ca_out_b + i * 512,
                      QKV, SC, AO, PR);
        ln_k<<<256, 256, 0, stream>>>(Y, PR, dec_ln2_s + i * 512, dec_ln2_b + i * 512, Y);

        run_ffn(stream, Y,
                dec_ff1_w + (long)i * 2048 * 512, dec_ff1_b + i * 2048,
                dec_ff2_w + (long)i * 512 * 2048, dec_ff2_b + i * 512, F1, F2);
        ln_k<<<256, 256, 0, stream>>>(Y, F2, dec_ln3_s + i * 512, dec_ln3_b + i * 512, Y);
    }

    // final norm -> attention_out (second output), then n = rownorm, gram = n@n^T
    ln_k<<<256, 256, 0, stream>>>(Y, nullptr, dec_norm_s, dec_norm_b, out_attn);
    l2norm_k<<<256, 256, 0, stream>>>(out_attn, NB);
    gemm_launch(stream, true, false, NB, 512, 0, NB, 512, 0, nullptr,
                out_gram, 1024, 0, 1024, 1024, 512, 1.0f, 1);
}

// Round 2
// 2012.231 us; speedup vs baseline: 3.3372x; 3.3372x over previous
//
#include <hip/hip_runtime.h>

// MyTransformer: 6-enc + 6-dec transformer, S=1024, D=512, H=8x64, FF=2048.
// Round 1: all GEMMs -> bf16 MFMA (16x16x32, fp32 acc), single-wave 64x64 tiles,
// XOR-swizzled LDS (conflict-free ds_read_b128). Scores/softmax/LN/residual fp32.
// Weights pre-converted to bf16 in ws (fallback: per-use rotating slots).

#define NLAY 6

typedef __attribute__((ext_vector_type(8))) short short8;
typedef __attribute__((ext_vector_type(4))) short short4v;
typedef __attribute__((ext_vector_type(4))) float f32x4;

__device__ inline unsigned short f2bu(float x) {
    unsigned u = __builtin_bit_cast(unsigned, x);
    unsigned r = (u + 0x7fffu + ((u >> 16) & 1u)) >> 16;   // RNE
    return (unsigned short)r;
}

// ---------------- fp32 -> bf16 bulk conversion (weights) ---------------------
__global__ __launch_bounds__(256)
void f2b_k(const float* __restrict__ s, unsigned short* __restrict__ d, long n)
{
    const long stride = (long)gridDim.x * 256;
    for (long i = (long)blockIdx.x * 256 + threadIdx.x; i * 8 < n; i += stride) {
        const long o = i * 8;
        const float4 a = *(const float4*)(s + o);
        const float4 b = *(const float4*)(s + o + 4);
        short8 v;
        v[0] = (short)f2bu(a.x); v[1] = (short)f2bu(a.y);
        v[2] = (short)f2bu(a.z); v[3] = (short)f2bu(a.w);
        v[4] = (short)f2bu(b.x); v[5] = (short)f2bu(b.y);
        v[6] = (short)f2bu(b.z); v[7] = (short)f2bu(b.w);
        *(short8*)(d + o) = v;
    }
}

// ---------------- MFMA GEMM: C = alpha * A @ B^T + bias ----------------------
// A: [M][K] bf16 row-major (lda), B: [N][K] bf16 row-major (ldb).
// One wave (64 thr) per 64x64 output tile. BK=64, XOR-swizzled LDS.
// OBF16: write bf16, else fp32. Batched via blockIdx.z with strides sA/sB/sC.
template<bool RELU, bool OBF16>
__global__ __launch_bounds__(64)
void gemm_mfma(const unsigned short* __restrict__ A, int lda, long sA,
               const unsigned short* __restrict__ B, int ldb, long sB,
               const float* __restrict__ bias,
               void* __restrict__ Cv, int ldc, long sC,
               int K, float alpha)
{
    __shared__ __align__(16) short As[64 * 64];
    __shared__ __align__(16) short Bs[64 * 64];
    const int bz = blockIdx.z;
    A += (long)bz * sA;  B += (long)bz * sB;
    const int m0 = blockIdx.y * 64;
    const int n0 = blockIdx.x * 64;
    const int l  = threadIdx.x;

    f32x4 acc[4][4] = {};

    const int srow  = l >> 3;    // 0..7: row within 8-row group
    const int sslot = l & 7;     // 0..7: 16B slot within 128B row
    const int fr    = l & 15;    // fragment row/col
    const int kc    = l >> 4;    // 0..3: k-chunk of 8

    for (int k0 = 0; k0 < K; k0 += 64) {
        #pragma unroll
        for (int i = 0; i < 8; ++i) {
            const int row = i * 8 + srow;
            const int kk  = (sslot ^ (row & 7)) * 8;   // pre-swizzled source k
            *(short8*)&As[row * 64 + sslot * 8] =
                *(const short8*)(A + (long)(m0 + row) * lda + k0 + kk);
        }
        #pragma unroll
        for (int i = 0; i < 8; ++i) {
            const int row = i * 8 + srow;
            const int kk  = (sslot ^ (row & 7)) * 8;
            *(short8*)&Bs[row * 64 + sslot * 8] =
                *(const short8*)(B + (long)(n0 + row) * ldb + k0 + kk);
        }
        __syncthreads();
        #pragma unroll
        for (int ks = 0; ks < 2; ++ks) {
            short8 af[4], bf[4];
            #pragma unroll
            for (int r = 0; r < 4; ++r) {
                const int row = r * 16 + fr;
                const int sl  = ((ks * 4 + kc) ^ (row & 7)) * 8;
                af[r] = *(const short8*)&As[row * 64 + sl];
                bf[r] = *(const short8*)&Bs[row * 64 + sl];
            }
            #pragma unroll
            for (int r = 0; r < 4; ++r)
                #pragma unroll
                for (int c = 0; c < 4; ++c)
                    acc[r][c] = __builtin_amdgcn_mfma_f32_16x16x32_bf16(af[r], bf[c], acc[r][c], 0, 0, 0);
        }
        __syncthreads();
    }

    const int cr = (l >> 4) * 4;   // C row base: (lane>>4)*4 + i, col = lane&15
    #pragma unroll
    for (int c = 0; c < 4; ++c) {
        const int n = n0 + c * 16 + fr;
        const float bv = bias ? bias[n] : 0.0f;
        #pragma unroll
        for (int r = 0; r < 4; ++r) {
            #pragma unroll
            for (int i = 0; i < 4; ++i) {
                const long m = m0 + r * 16 + cr + i;
                float v = acc[r][c][i] * alpha + bv;
                if (RELU) v = fmaxf(v, 0.0f);
                if (OBF16) ((unsigned short*)Cv)[bz * sC + m * ldc + n] = f2bu(v);
                else       ((float*)Cv)[bz * sC + m * ldc + n] = v;
            }
        }
    }
}

// ------------- V transpose: QKVb[s][1024+h*64+d] -> VT[h][d][s] (bf16) -------
__global__ __launch_bounds__(256)
void vtrans_k(const unsigned short* __restrict__ QKVb, unsigned short* __restrict__ VT)
{
    __shared__ short t[64][72];
    const int h  = blockIdx.y;
    const int s0 = blockIdx.x * 64;
    const int tid = threadIdx.x;
    #pragma unroll
    for (int it = 0; it < 2; ++it) {
        const int idx = it * 256 + tid;       // 0..511
        const int row = idx >> 3;             // s 0..63
        const int c8  = (idx & 7) * 8;        // d
        const short8 v = *(const short8*)(QKVb + (long)(s0 + row) * 1536 + 1024 + h * 64 + c8);
        #pragma unroll
        for (int j = 0; j < 8; ++j) t[c8 + j][row] = v[j];
    }
    __syncthreads();
    #pragma unroll
    for (int it = 0; it < 2; ++it) {
        const int idx = it * 256 + tid;
        const int dd  = idx >> 3;
        const int s8  = (idx & 7) * 8;
        short8 o;
        #pragma unroll
        for (int j = 0; j < 8; ++j) o[j] = t[dd][s8 + j];
        *(short8*)(VT + (long)h * 64 * 1024 + (long)dd * 1024 + s0 + s8) = o;
    }
}

// -------- softmax rows of 1024: fp32 in -> bf16 out (one wave / row) ---------
__global__ __launch_bounds__(256)
void softmax_k(const float* __restrict__ Sc, unsigned short* __restrict__ P)
{
    const int lane = threadIdx.x & 63;
    const int row  = (blockIdx.x << 2) + (threadIdx.x >> 6);
    const float* p = Sc + (long)row * 1024;
    unsigned short* o = P + (long)row * 1024;
    float v[16];
    float mx = -3.4e38f;
    #pragma unroll
    for (int i = 0; i < 16; ++i) { v[i] = p[lane + (i << 6)]; mx = fmaxf(mx, v[i]); }
    #pragma unroll
    for (int off = 32; off; off >>= 1) mx = fmaxf(mx, __shfl_xor(mx, off));
    float sum = 0.f;
    #pragma unroll
    for (int i = 0; i < 16; ++i) { v[i] = __expf(v[i] - mx); sum += v[i]; }
    #pragma unroll
    for (int off = 32; off; off >>= 1) sum += __shfl_xor(sum, off);
    const float inv = 1.0f / sum;
    #pragma unroll
    for (int i = 0; i < 16; ++i) o[lane + (i << 6)] = f2bu(v[i] * inv);
}

// -------- LayerNorm rows of 512: out fp32 (+ optional bf16 copy) -------------
__global__ __launch_bounds__(256)
void ln_k(const float* __restrict__ x, const float* __restrict__ a,
          const float* __restrict__ s, const float* __restrict__ b,
          float* __restrict__ out, unsigned short* __restrict__ outb)
{
    const int lane = threadIdx.x & 63;
    const int row  = (blockIdx.x << 2) + (threadIdx.x >> 6);
    const float* px = x + (long)row * 512;
    float v[8];
    float sum = 0.f;
    #pragma unroll
    for (int i = 0; i < 8; ++i) {
        v[i] = px[lane + (i << 6)];
        if (a) v[i] += a[(long)row * 512 + lane + (i << 6)];
        sum += v[i];
    }
    #pragma unroll
    for (int off = 32; off; off >>= 1) sum += __shfl_xor(sum, off);
    const float m = sum * (1.0f / 512.0f);
    float s2 = 0.f;
    #pragma unroll
    for (int i = 0; i < 8; ++i) { const float d = v[i] - m; s2 += d * d; }
    #pragma unroll
    for (int off = 32; off; off >>= 1) s2 += __shfl_xor(s2, off);
    const float inv = rsqrtf(s2 * (1.0f / 512.0f) + 1e-5f);
    #pragma unroll
    for (int i = 0; i < 8; ++i) {
        const int j = lane + (i << 6);
        const float r = (v[i] - m) * inv * s[j] + b[j];
        out[(long)row * 512 + j] = r;
        if (outb) outb[(long)row * 512 + j] = f2bu(r);
    }
}

// -------- L2 row-normalize rows of 512 -> bf16 -------------------------------
__global__ __launch_bounds__(256)
void l2norm_k(const float* __restrict__ x, unsigned short* __restrict__ out)
{
    const int lane = threadIdx.x & 63;
    const int row  = (blockIdx.x << 2) + (threadIdx.x >> 6);
    const float* px = x + (long)row * 512;
    float v[8];
    float s2 = 0.f;
    #pragma unroll
    for (int i = 0; i < 8; ++i) { v[i] = px[lane + (i << 6)]; s2 += v[i] * v[i]; }
    #pragma unroll
    for (int off = 32; off; off >>= 1) s2 += __shfl_xor(s2, off);
    const float inv = rsqrtf(s2);
    #pragma unroll
    for (int i = 0; i < 8; ++i) out[(long)row * 512 + lane + (i << 6)] = f2bu(v[i] * inv);
}

// -------- init: x -> MEMf, Yf (fp32) + MEMb, Yb (bf16) -----------------------
__global__ __launch_bounds__(256)
void init_k(const float* __restrict__ x, float* __restrict__ mf, float* __restrict__ yf,
            unsigned short* __restrict__ mb, unsigned short* __restrict__ yb)
{
    const long i = ((long)blockIdx.x * 256 + threadIdx.x) * 4;
    const float4 v = *(const float4*)(x + i);
    *(float4*)(mf + i) = v;
    *(float4*)(yf + i) = v;
    short4v s;
    s[0] = (short)f2bu(v.x); s[1] = (short)f2bu(v.y);
    s[2] = (short)f2bu(v.z); s[3] = (short)f2bu(v.w);
    *(short4v*)(mb + i) = s;
    *(short4v*)(yb + i) = s;
}

// ------------------------------ host side ------------------------------------
static void mfma_launch(hipStream_t st, bool relu, bool obf16,
                        const unsigned short* A, int lda, long sA,
                        const unsigned short* B, int ldb, long sB,
                        const float* bias, void* C, int ldc, long sC,
                        int M, int N, int K, float alpha, int batch)
{
    dim3 g(N / 64, M / 64, batch);
    if (obf16) {
        if (relu) gemm_mfma<true,  true ><<<g, 64, 0, st>>>(A, lda, sA, B, ldb, sB, bias, C, ldc, sC, K, alpha);
        else      gemm_mfma<false, true ><<<g, 64, 0, st>>>(A, lda, sA, B, ldb, sB, bias, C, ldc, sC, K, alpha);
    } else {
        if (relu) gemm_mfma<true,  false><<<g, 64, 0, st>>>(A, lda, sA, B, ldb, sB, bias, C, ldc, sC, K, alpha);
        else      gemm_mfma<false, false><<<g, 64, 0, st>>>(A, lda, sA, B, ldb, sB, bias, C, ldc, sC, K, alpha);
    }
}

extern "C" void kernel_launch(void* const* d_in, const int* in_sizes, int n_in,
                              void* d_out, int out_size, void* d_ws, size_t ws_size,
                              hipStream_t stream)
{
    const float* x            = (const float*)d_in[0];
    const float* enc_qkv_w    = (const float*)d_in[1];
    const float* enc_qkv_b    = (const float*)d_in[2];
    const float* enc_out_w    = (const float*)d_in[3];
    const float* enc_out_b    = (const float*)d_in[4];
    const float* enc_ff1_w    = (const float*)d_in[5];
    const float* enc_ff1_b    = (const float*)d_in[6];
    const float* enc_ff2_w    = (const float*)d_in[7];
    const float* enc_ff2_b    = (const float*)d_in[8];
    const float* enc_ln1_s    = (const float*)d_in[9];
    const float* enc_ln1_b    = (const float*)d_in[10];
    const float* enc_ln2_s    = (const float*)d_in[11];
    const float* enc_ln2_b    = (const float*)d_in[12];
    const float* dec_sa_qkv_w = (const float*)d_in[13];
    const float* dec_sa_qkv_b = (const float*)d_in[14];
    const float* dec_sa_out_w = (const float*)d_in[15];
    const float* dec_sa_out_b = (const float*)d_in[16];
    const float* dec_ca_qkv_w = (const float*)d_in[17];
    const float* dec_ca_qkv_b = (const float*)d_in[18];
    const float* dec_ca_out_w = (const float*)d_in[19];
    const float* dec_ca_out_b = (const float*)d_in[20];
    const float* dec_ff1_w    = (const float*)d_in[21];
    const float* dec_ff1_b    = (const float*)d_in[22];
    const float* dec_ff2_w    = (const float*)d_in[23];
    const float* dec_ff2_b    = (const float*)d_in[24];
    const float* dec_ln1_s    = (const float*)d_in[25];
    const float* dec_ln1_b    = (const float*)d_in[26];
    const float* dec_ln2_s    = (const float*)d_in[27];
    const float* dec_ln2_b    = (const float*)d_in[28];
    const float* dec_ln3_s    = (const float*)d_in[29];
    const float* dec_ln3_b    = (const float*)d_in[30];
    const float* enc_norm_s   = (const float*)d_in[31];
    const float* enc_norm_b   = (const float*)d_in[32];
    const float* dec_norm_s   = (const float*)d_in[33];
    const float* dec_norm_b   = (const float*)d_in[34];

    // ------------------------- workspace layout ------------------------------
    char* p = (char*)d_ws;
    auto alloc = [&](size_t bytes) -> char* {
        char* r = p; p += (bytes + 255) & ~(size_t)255; return r;
    };
    float*          MEMf = (float*)alloc(1024 * 512 * 4);
    float*          Yf   = (float*)alloc(1024 * 512 * 4);
    unsigned short* MEMb = (unsigned short*)alloc(1024 * 512 * 2);
    unsigned short* Yb   = (unsigned short*)alloc(1024 * 512 * 2);
    unsigned short* QKVb = (unsigned short*)alloc(1024 * 1536 * 2);
    unsigned short* VT   = (unsigned short*)alloc(8L * 64 * 1024 * 2);
    float*          SC   = (float*)alloc(8L * 1024 * 1024 * 4);
    unsigned short* Pb   = (unsigned short*)alloc(8L * 1024 * 1024 * 2);
    unsigned short* AOb  = (unsigned short*)alloc(1024 * 512 * 2);
    float*          PR   = (float*)alloc(1024 * 512 * 4);
    unsigned short* F1b  = (unsigned short*)alloc(1024L * 2048 * 2);
    float*          F2   = (float*)alloc(1024 * 512 * 4);
    unsigned short* NBb  = (unsigned short*)alloc(1024 * 512 * 2);

    // weights: 10 tensors x 6 layers
    const float* wsrc[10] = {enc_qkv_w, enc_out_w, enc_ff1_w, enc_ff2_w,
                             dec_sa_qkv_w, dec_sa_out_w, dec_ca_qkv_w, dec_ca_out_w,
                             dec_ff1_w, dec_ff2_w};
    const long wper[10] = {1536L*512, 512L*512, 2048L*512, 512L*2048,
                           1536L*512, 512L*512, 1536L*512, 512L*512,
                           2048L*512, 512L*2048};
    long wtot = 0;
    for (int t = 0; t < 10; ++t) wtot += wper[t] * NLAY;

    const size_t used = (size_t)(p - (char*)d_ws);
    const bool preconv = (ws_size > used) && ((ws_size - used) >= (size_t)wtot * 2 + 4096);

    unsigned short* wpre[10] = {};
    unsigned short* slots[2] = {};
    int slot_ctr = 0;
    if (preconv) {
        for (int t = 0; t < 10; ++t) {
            wpre[t] = (unsigned short*)alloc((size_t)wper[t] * NLAY * 2);
            long n = wper[t] * NLAY;
            long blocks = (n / 8 + 255) / 256; if (blocks > 2048) blocks = 2048;
            f2b_k<<<dim3((unsigned)blocks), 256, 0, stream>>>(wsrc[t], wpre[t], n);
        }
    } else {
        slots[0] = (unsigned short*)alloc(2048L * 512 * 2);
        slots[1] = (unsigned short*)alloc(2048L * 512 * 2);
    }
    auto W = [&](int t, int layer) -> const unsigned short* {
        if (preconv) return wpre[t] + (long)layer * wper[t];
        unsigned short* dst = slots[(slot_ctr++) & 1];
        const long n = wper[t];
        long blocks = (n / 8 + 255) / 256; if (blocks > 2048) blocks = 2048;
        f2b_k<<<dim3((unsigned)blocks), 256, 0, stream>>>(wsrc[t] + (long)layer * wper[t], dst, n);
        return dst;
    };

    float* out_gram = (float*)d_out;              // 1024x1024
    float* out_attn = out_gram + 1024 * 1024;     // 1024x512

    // attention: qb/kvb bf16 inputs -> PR (fp32)
    auto run_attn = [&](const unsigned short* qb, const unsigned short* kvb,
                        int wt_qkv, int wt_o, int layer,
                        const float* bqkv, const float* bo) {
        if (qb == kvb) {
            mfma_launch(stream, false, true, qb, 512, 0, W(wt_qkv, layer), 512, 0, bqkv,
                        QKVb, 1536, 0, 1024, 1536, 512, 1.0f, 1);
        } else {
            const unsigned short* wq = W(wt_qkv, layer);
            mfma_launch(stream, false, true, qb, 512, 0, wq, 512, 0, bqkv,
                        QKVb, 1536, 0, 1024, 512, 512, 1.0f, 1);
            mfma_launch(stream, false, true, kvb, 512, 0, wq + 512L * 512, 512, 0, bqkv + 512,
                        QKVb + 512, 1536, 0, 1024, 1024, 512, 1.0f, 1);
        }
        vtrans_k<<<dim3(16, 8), 256, 0, stream>>>(QKVb, VT);
        // scores[h] = (1/8) Q_h @ K_h^T : A=Q (off h*64), B=K (off 512+h*64)
        mfma_launch(stream, false, false, QKVb, 1536, 64, QKVb + 512, 1536, 64, nullptr,
                    SC, 1024, 1024L * 1024, 1024, 1024, 64, 0.125f, 8);
        softmax_k<<<2048, 256, 0, stream>>>(SC, Pb);
        // AO[:, h*64:+64] = P_h @ VT_h^T
        mfma_launch(stream, false, true, Pb, 1024, 1024L * 1024, VT, 1024, 64L * 1024, nullptr,
                    AOb, 512, 64, 1024, 64, 1024, 1.0f, 8);
        mfma_launch(stream, false, false, AOb, 512, 0, W(wt_o, layer), 512, 0, bo,
                    PR, 512, 0, 1024, 512, 512, 1.0f, 1);
    };

    init_k<<<512, 256, 0, stream>>>(x, MEMf, Yf, MEMb, Yb);

    // ----------------------------- encoder -----------------------------------
    for (int i = 0; i < NLAY; ++i) {
        run_attn(MEMb, MEMb, 0, 1, i, enc_qkv_b + i * 1536, enc_out_b + i * 512);
        ln_k<<<256, 256, 0, stream>>>(MEMf, PR, enc_ln1_s + i * 512, enc_ln1_b + i * 512, MEMf, MEMb);
        mfma_launch(stream, true,  true,  MEMb, 512, 0, W(2, i), 512, 0, enc_ff1_b + i * 2048,
                    F1b, 2048, 0, 1024, 2048, 512, 1.0f, 1);
        mfma_launch(stream, false, false, F1b, 2048, 0, W(3, i), 2048, 0, enc_ff2_b + i * 512,
                    F2, 512, 0, 1024, 512, 2048, 1.0f, 1);
        ln_k<<<256, 256, 0, stream>>>(MEMf, F2, enc_ln2_s + i * 512, enc_ln2_b + i * 512, MEMf, MEMb);
    }
    ln_k<<<256, 256, 0, stream>>>(MEMf, nullptr, enc_norm_s, enc_norm_b, MEMf, MEMb);

    // ----------------------------- decoder -----------------------------------
    for (int i = 0; i < NLAY; ++i) {
        run_attn(Yb, Yb, 4, 5, i, dec_sa_qkv_b + i * 1536, dec_sa_out_b + i * 512);
        ln_k<<<256, 256, 0, stream>>>(Yf, PR, dec_ln1_s + i * 512, dec_ln1_b + i * 512, Yf, Yb);

        run_attn(Yb, MEMb, 6, 7, i, dec_ca_qkv_b + i * 1536, dec_ca_out_b + i * 512);
        ln_k<<<256, 256, 0, stream>>>(Yf, PR, dec_ln2_s + i * 512, dec_ln2_b + i * 512, Yf, Yb);

        mfma_launch(stream, true,  true,  Yb, 512, 0, W(8, i), 512, 0, dec_ff1_b + i * 2048,
                    F1b, 2048, 0, 1024, 2048, 512, 1.0f, 1);
        mfma_launch(stream, false, false, F1b, 2048, 0, W(9, i), 2048, 0, dec_ff2_b + i * 512,
                    F2, 512, 0, 1024, 512, 2048, 1.0f, 1);
        ln_k<<<256, 256, 0, stream>>>(Yf, F2, dec_ln3_s + i * 512, dec_ln3_b + i * 512, Yf, Yb);
    }

    // final: attention_out, n = rownorm, gram = n@n^T
    ln_k<<<256, 256, 0, stream>>>(Yf, nullptr, dec_norm_s, dec_norm_b, out_attn, nullptr);
    l2norm_k<<<256, 256, 0, stream>>>(out_attn, NBb);
    mfma_launch(stream, false, false, NBb, 512, 0, NBb, 512, 0, nullptr,
                out_gram, 1024, 0, 1024, 1024, 512, 1.0f, 1);
}

// Round 3
// 1601.801 us; speedup vs baseline: 4.1922x; 1.2562x over previous
//
#include <hip/hip_runtime.h>

// MyTransformer: 6-enc + 6-dec, S=1024, D=512, H=8x64, FF=2048.
// Round 2: 4-wave GEMM (M-split, 64x64 tile, BK=64) with global_load_lds +
// double-buffer + counted vmcnt; fused flash attention (QK^T+softmax+PV);
// V-transpose fused into QKV GEMM epilogue. LN/residual fp32.

#define NLAY 6

typedef __attribute__((ext_vector_type(8))) short short8;
typedef __attribute__((ext_vector_type(4))) short short4v;
typedef __attribute__((ext_vector_type(4))) float f32x4;

typedef __attribute__((address_space(3))) short lds_short;
typedef __attribute__((address_space(1))) const unsigned short g_ushort;

__device__ __forceinline__ void gload16(const unsigned short* g, short* l) {
    __builtin_amdgcn_global_load_lds((g_ushort*)g, (lds_short*)l, 16, 0, 0);
}

__device__ inline unsigned short f2bu(float x) {
    unsigned u = __builtin_bit_cast(unsigned, x);
    unsigned r = (u + 0x7fffu + ((u >> 16) & 1u)) >> 16;   // RNE
    return (unsigned short)r;
}

// ---------------- fp32 -> bf16 bulk conversion (weights) ---------------------
__global__ __launch_bounds__(256)
void f2b_k(const float* __restrict__ s, unsigned short* __restrict__ d, long n)
{
    const long stride = (long)gridDim.x * 256;
    for (long i = (long)blockIdx.x * 256 + threadIdx.x; i * 8 < n; i += stride) {
        const long o = i * 8;
        const float4 a = *(const float4*)(s + o);
        const float4 b = *(const float4*)(s + o + 4);
        short8 v;
        v[0] = (short)f2bu(a.x); v[1] = (short)f2bu(a.y);
        v[2] = (short)f2bu(a.z); v[3] = (short)f2bu(a.w);
        v[4] = (short)f2bu(b.x); v[5] = (short)f2bu(b.y);
        v[6] = (short)f2bu(b.z); v[7] = (short)f2bu(b.w);
        *(short8*)(d + o) = v;
    }
}

// ---------------- 4-wave MFMA GEMM: C = alpha * A @ B^T + bias ---------------
// A: [M][K] bf16 (lda), B: [N][K] bf16 (ldb). Block = 256 thr = 4 waves,
// tile 64x64, wave w owns rows [w*16, w*16+16). BK=64, double-buffered LDS
// filled by global_load_lds (linear dest, pre-swizzled source). K >= 128.
// Optional VT scatter: for output cols n >= vt_col0, also write
// VTp[h][d][m] (h=(n-vt_col0)>>6, d=(n-vt_col0)&63) as bf16.
template<bool RELU, bool OBF16>
__global__ __launch_bounds__(256)
void gemm4_k(const unsigned short* __restrict__ A, int lda, long sA,
             const unsigned short* __restrict__ B, int ldb, long sB,
             const float* __restrict__ bias,
             void* __restrict__ Cv, int ldc, long sC,
             int K, float alpha,
             unsigned short* __restrict__ VTp, int vt_col0)
{
    __shared__ __align__(16) short As[2][64 * 64];
    __shared__ __align__(16) short Bs[2][64 * 64];
    const int bz = blockIdx.z;
    A += (long)bz * sA;  B += (long)bz * sB;
    const int m0 = blockIdx.y * 64;
    const int n0 = blockIdx.x * 64;
    const int tid = threadIdx.x;
    const int w  = tid >> 6;
    const int l  = tid & 63;
    const int fr = l & 15;
    const int kc = l >> 4;

    const int srow = w * 16 + (l >> 3);   // staged row (this wave covers 16 rows)
    const int ssl  = ((l & 7) ^ (srow & 7)) * 8;   // pre-swizzled k-slot (elements)

    f32x4 acc[4] = {};
    const int T = K >> 6;

    // FILL(t): 4 global_load_lds per wave (2 A-rows-of-8, 2 B-rows-of-8)
    auto FILL = [&](int t) {
        const int buf = t & 1;
        const int k0 = t * 64;
        #pragma unroll
        for (int it = 0; it < 2; ++it) {
            const int row = srow + it * 8;
            const int sl  = ((l & 7) ^ (row & 7)) * 8;
            gload16(A + (long)(m0 + row) * lda + k0 + sl, &As[buf][(w * 16 + it * 8) * 64]);
            gload16(B + (long)(n0 + row) * ldb + k0 + sl, &Bs[buf][(w * 16 + it * 8) * 64]);
        }
    };

    FILL(0); FILL(1);
    for (int t = 0; t < T; ++t) {
        const int buf = t & 1;
        if (t == T - 1) asm volatile("s_waitcnt vmcnt(0)" ::: "memory");
        else            asm volatile("s_waitcnt vmcnt(4)" ::: "memory");
        __builtin_amdgcn_sched_barrier(0);
        __builtin_amdgcn_s_barrier();
        #pragma unroll
        for (int ks = 0; ks < 2; ++ks) {
            const int arow = w * 16 + fr;
            const short8 af = *(const short8*)&As[buf][arow * 64 + (((ks * 4 + kc) ^ (arow & 7)) * 8)];
            #pragma unroll
            for (int c = 0; c < 4; ++c) {
                const int brow = c * 16 + fr;
                const short8 bf = *(const short8*)&Bs[buf][brow * 64 + (((ks * 4 + kc) ^ (brow & 7)) * 8)];
                acc[c] = __builtin_amdgcn_mfma_f32_16x16x32_bf16(af, bf, acc[c], 0, 0, 0);
            }
        }
        __builtin_amdgcn_s_barrier();
        if (t + 2 < T) FILL(t + 2);
    }

    // epilogue: wave w stores its 16 rows
    #pragma unroll
    for (int c = 0; c < 4; ++c) {
        const int n = n0 + c * 16 + fr;
        const float bv = bias ? bias[n] : 0.0f;
        const bool do_vt = (VTp != nullptr) && (n >= vt_col0);
        #pragma unroll
        for (int i = 0; i < 4; ++i) {
            const long m = m0 + w * 16 + kc * 4 + i;
            float v = acc[c][i] * alpha + bv;
            if (RELU) v = fmaxf(v, 0.0f);
            if (OBF16) ((unsigned short*)Cv)[bz * sC + m * ldc + n] = f2bu(v);
            else       ((float*)Cv)[bz * sC + m * ldc + n] = v;
            if (do_vt) {
                const int vc = n - vt_col0;
                VTp[(long)(vc >> 6) * 65536 + (long)(vc & 63) * 1024 + m] = f2bu(v);
            }
        }
    }
}

// ---------------- fused attention: O = softmax(QK^T/8) V ---------------------
// Grid (16 q-tiles, 8 heads), 256 thr = 4 waves; wave w owns q rows
// qt*64+w*16..+16. Q in regs; K (from QKVb) and V (from VT, i.e. [d][s])
// double-buffered in LDS via global_load_lds; online softmax in-register;
// P bounced through wave-private swizzled LDS into MFMA A-frags.
__global__ __launch_bounds__(256)
void attn_k(const unsigned short* __restrict__ QKVb,   // [1024][1536] (Q|K|V)
            const unsigned short* __restrict__ VT,     // [8][64][1024]
            unsigned short* __restrict__ AOb)          // [1024][512]
{
    __shared__ __align__(16) short Ks[2][64 * 64];
    __shared__ __align__(16) short Vs[2][64 * 64];     // rows = d, cols = s
    __shared__ __align__(16) short Ps[4][16 * 64];     // wave-private P tiles
    const int qt = blockIdx.x;
    const int h  = blockIdx.y;
    const int tid = threadIdx.x;
    const int w  = tid >> 6;
    const int l  = tid & 63;
    const int fr = l & 15;
    const int kc = l >> 4;

    // Q fragments: rows qt*64 + w*16 + fr, k-chunks ks*32 + kc*8
    const int qrow = qt * 64 + w * 16 + fr;
    short8 qf[2];
    qf[0] = *(const short8*)(QKVb + (long)qrow * 1536 + h * 64 + kc * 8);
    qf[1] = *(const short8*)(QKVb + (long)qrow * 1536 + h * 64 + 32 + kc * 8);

    auto FILL = [&](int t) {
        const int buf = t & 1;
        const int kb = t * 64;
        #pragma unroll
        for (int it = 0; it < 2; ++it) {
            const int row = w * 16 + it * 8 + (l >> 3);
            const int sl  = ((l & 7) ^ (row & 7)) * 8;
            gload16(QKVb + (long)(kb + row) * 1536 + 512 + h * 64 + sl,
                    &Ks[buf][(w * 16 + it * 8) * 64]);
            gload16(VT + (long)h * 65536 + (long)row * 1024 + kb + sl,
                    &Vs[buf][(w * 16 + it * 8) * 64]);
        }
    };

    float m_i[4], l_i[4];
    f32x4 acc_o[4] = {};
    #pragma unroll
    for (int i = 0; i < 4; ++i) { m_i[i] = -1e30f; l_i[i] = 0.f; }

    short* ps = &Ps[w][0];

    FILL(0); FILL(1);
    for (int t = 0; t < 16; ++t) {
        const int buf = t & 1;
        if (t == 15) asm volatile("s_waitcnt vmcnt(0)" ::: "memory");
        else         asm volatile("s_waitcnt vmcnt(4)" ::: "memory");
        __builtin_amdgcn_sched_barrier(0);
        __builtin_amdgcn_s_barrier();

        // S = Q @ K^T  (16q x 64k)
        f32x4 sacc[4] = {};
        #pragma unroll
        for (int ks = 0; ks < 2; ++ks) {
            #pragma unroll
            for (int c = 0; c < 4; ++c) {
                const int krow = c * 16 + fr;
                const short8 kf = *(const short8*)&Ks[buf][krow * 64 + (((ks * 4 + kc) ^ (krow & 7)) * 8)];
                sacc[c] = __builtin_amdgcn_mfma_f32_16x16x32_bf16(qf[ks], kf, sacc[c], 0, 0, 0);
            }
        }

        // online softmax (scale 1/8); rows are lane-local per 16-lane group
        float p[4][4];
        #pragma unroll
        for (int i = 0; i < 4; ++i) {
            float tm = fmaxf(fmaxf(sacc[0][i], sacc[1][i]), fmaxf(sacc[2][i], sacc[3][i]));
            #pragma unroll
            for (int off = 8; off; off >>= 1) tm = fmaxf(tm, __shfl_xor(tm, off));
            tm *= 0.125f;
            const float mn = fmaxf(m_i[i], tm);
            const float sc = __expf(m_i[i] - mn);
            m_i[i] = mn;
            float ts = 0.f;
            #pragma unroll
            for (int c = 0; c < 4; ++c) { p[c][i] = __expf(sacc[c][i] * 0.125f - mn); ts += p[c][i]; }
            #pragma unroll
            for (int off = 8; off; off >>= 1) ts += __shfl_xor(ts, off);
            l_i[i] = l_i[i] * sc + ts;
            #pragma unroll
            for (int c = 0; c < 4; ++c) acc_o[c][i] *= sc;
        }

        // P -> wave-private LDS (bf16, swizzled at 8-elem granularity)
        #pragma unroll
        for (int c = 0; c < 4; ++c) {
            const int col = c * 16 + fr;
            #pragma unroll
            for (int i = 0; i < 4; ++i) {
                const int row = kc * 4 + i;
                ps[row * 64 + (((col >> 3) ^ (row & 7)) * 8) + (col & 7)] = (short)f2bu(p[c][i]);
            }
        }
        // P A-frags: row = fr, k-chunk ks*4+kc
        short8 pf[2];
        pf[0] = *(const short8*)&ps[fr * 64 + ((kc ^ (fr & 7)) * 8)];
        pf[1] = *(const short8*)&ps[fr * 64 + (((4 + kc) ^ (fr & 7)) * 8)];

        // O += P @ V  (V from Vs[d][s])
        #pragma unroll
        for (int ks = 0; ks < 2; ++ks) {
            #pragma unroll
            for (int c = 0; c < 4; ++c) {
                const int drow = c * 16 + fr;
                const short8 vf = *(const short8*)&Vs[buf][drow * 64 + (((ks * 4 + kc) ^ (drow & 7)) * 8)];
                acc_o[c] = __builtin_amdgcn_mfma_f32_16x16x32_bf16(pf[ks], vf, acc_o[c], 0, 0, 0);
            }
        }
        __builtin_amdgcn_s_barrier();
        if (t < 14) FILL(t + 2);
    }

    // write O / l  -> AOb[q][h*64+d] bf16
    #pragma unroll
    for (int c = 0; c < 4; ++c) {
        const int dcol = h * 64 + c * 16 + fr;
        #pragma unroll
        for (int i = 0; i < 4; ++i) {
            const int row = qt * 64 + w * 16 + kc * 4 + i;
            AOb[(long)row * 512 + dcol] = f2bu(acc_o[c][i] / l_i[i]);
        }
    }
}

// -------- LayerNorm rows of 512: out fp32 (+ optional bf16 copy) -------------
__global__ __launch_bounds__(256)
void ln_k(const float* __restrict__ x, const float* __restrict__ a,
          const float* __restrict__ s, const float* __restrict__ b,
          float* __restrict__ out, unsigned short* __restrict__ outb)
{
    const int lane = threadIdx.x & 63;
    const int row  = (blockIdx.x << 2) + (threadIdx.x >> 6);
    const float* px = x + (long)row * 512;
    float v[8];
    float sum = 0.f;
    #pragma unroll
    for (int i = 0; i < 8; ++i) {
        v[i] = px[lane + (i << 6)];
        if (a) v[i] += a[(long)row * 512 + lane + (i << 6)];
        sum += v[i];
    }
    #pragma unroll
    for (int off = 32; off; off >>= 1) sum += __shfl_xor(sum, off);
    const float m = sum * (1.0f / 512.0f);
    float s2 = 0.f;
    #pragma unroll
    for (int i = 0; i < 8; ++i) { const float d = v[i] - m; s2 += d * d; }
    #pragma unroll
    for (int off = 32; off; off >>= 1) s2 += __shfl_xor(s2, off);
    const float inv = rsqrtf(s2 * (1.0f / 512.0f) + 1e-5f);
    #pragma unroll
    for (int i = 0; i < 8; ++i) {
        const int j = lane + (i << 6);
        const float r = (v[i] - m) * inv * s[j] + b[j];
        out[(long)row * 512 + j] = r;
        if (outb) outb[(long)row * 512 + j] = f2bu(r);
    }
}

// -------- L2 row-normalize rows of 512 -> bf16 -------------------------------
__global__ __launch_bounds__(256)
void l2norm_k(const float* __restrict__ x, unsigned short* __restrict__ out)
{
    const int lane = threadIdx.x & 63;
    const int row  = (blockIdx.x << 2) + (threadIdx.x >> 6);
    const float* px = x + (long)row * 512;
    float v[8];
    float s2 = 0.f;
    #pragma unroll
    for (int i = 0; i < 8; ++i) { v[i] = px[lane + (i << 6)]; s2 += v[i] * v[i]; }
    #pragma unroll
    for (int off = 32; off; off >>= 1) s2 += __shfl_xor(s2, off);
    const float inv = rsqrtf(s2);
    #pragma unroll
    for (int i = 0; i < 8; ++i) out[(long)row * 512 + lane + (i << 6)] = f2bu(v[i] * inv);
}

// -------- init: x -> MEMf, Yf (fp32) + MEMb, Yb (bf16) -----------------------
__global__ __launch_bounds__(256)
void init_k(const float* __restrict__ x, float* __restrict__ mf, float* __restrict__ yf,
            unsigned short* __restrict__ mb, unsigned short* __restrict__ yb)
{
    const long i = ((long)blockIdx.x * 256 + threadIdx.x) * 4;
    const float4 v = *(const float4*)(x + i);
    *(float4*)(mf + i) = v;
    *(float4*)(yf + i) = v;
    short4v s;
    s[0] = (short)f2bu(v.x); s[1] = (short)f2bu(v.y);
    s[2] = (short)f2bu(v.z); s[3] = (short)f2bu(v.w);
    *(short4v*)(mb + i) = s;
    *(short4v*)(yb + i) = s;
}

// ------------------------------ host side ------------------------------------
static void gemm4(hipStream_t st, bool relu, bool obf16,
                  const unsigned short* A, int lda, long sA,
                  const unsigned short* B, int ldb, long sB,
                  const float* bias, void* C, int ldc, long sC,
                  int M, int N, int K, float alpha, int batch,
                  unsigned short* VTp = nullptr, int vt_col0 = 0)
{
    dim3 g(N / 64, M / 64, batch);
    if (obf16) {
        if (relu) gemm4_k<true,  true ><<<g, 256, 0, st>>>(A, lda, sA, B, ldb, sB, bias, C, ldc, sC, K, alpha, VTp, vt_col0);
        else      gemm4_k<false, true ><<<g, 256, 0, st>>>(A, lda, sA, B, ldb, sB, bias, C, ldc, sC, K, alpha, VTp, vt_col0);
    } else {
        if (relu) gemm4_k<true,  false><<<g, 256, 0, st>>>(A, lda, sA, B, ldb, sB, bias, C, ldc, sC, K, alpha, VTp, vt_col0);
        else      gemm4_k<false, false><<<g, 256, 0, st>>>(A, lda, sA, B, ldb, sB, bias, C, ldc, sC, K, alpha, VTp, vt_col0);
    }
}

extern "C" void kernel_launch(void* const* d_in, const int* in_sizes, int n_in,
                              void* d_out, int out_size, void* d_ws, size_t ws_size,
                              hipStream_t stream)
{
    const float* x            = (const float*)d_in[0];
    const float* enc_qkv_w    = (const float*)d_in[1];
    const float* enc_qkv_b    = (const float*)d_in[2];
    const float* enc_out_w    = (const float*)d_in[3];
    const float* enc_out_b    = (const float*)d_in[4];
    const float* enc_ff1_w    = (const float*)d_in[5];
    const float* enc_ff1_b    = (const float*)d_in[6];
    const float* enc_ff2_w    = (const float*)d_in[7];
    const float* enc_ff2_b    = (const float*)d_in[8];
    const float* enc_ln1_s    = (const float*)d_in[9];
    const float* enc_ln1_b    = (const float*)d_in[10];
    const float* enc_ln2_s    = (const float*)d_in[11];
    const float* enc_ln2_b    = (const float*)d_in[12];
    const float* dec_sa_qkv_w = (const float*)d_in[13];
    const float* dec_sa_qkv_b = (const float*)d_in[14];
    const float* dec_sa_out_w = (const float*)d_in[15];
    const float* dec_sa_out_b = (const float*)d_in[16];
    const float* dec_ca_qkv_w = (const float*)d_in[17];
    const float* dec_ca_qkv_b = (const float*)d_in[18];
    const float* dec_ca_out_w = (const float*)d_in[19];
    const float* dec_ca_out_b = (const float*)d_in[20];
    const float* dec_ff1_w    = (const float*)d_in[21];
    const float* dec_ff1_b    = (const float*)d_in[22];
    const float* dec_ff2_w    = (const float*)d_in[23];
    const float* dec_ff2_b    = (const float*)d_in[24];
    const float* dec_ln1_s    = (const float*)d_in[25];
    const float* dec_ln1_b    = (const float*)d_in[26];
    const float* dec_ln2_s    = (const float*)d_in[27];
    const float* dec_ln2_b    = (const float*)d_in[28];
    const float* dec_ln3_s    = (const float*)d_in[29];
    const float* dec_ln3_b    = (const float*)d_in[30];
    const float* enc_norm_s   = (const float*)d_in[31];
    const float* enc_norm_b   = (const float*)d_in[32];
    const float* dec_norm_s   = (const float*)d_in[33];
    const float* dec_norm_b   = (const float*)d_in[34];

    char* p = (char*)d_ws;
    auto alloc = [&](size_t bytes) -> char* {
        char* r = p; p += (bytes + 255) & ~(size_t)255; return r;
    };
    float*          MEMf = (float*)alloc(1024 * 512 * 4);
    float*          Yf   = (float*)alloc(1024 * 512 * 4);
    unsigned short* MEMb = (unsigned short*)alloc(1024 * 512 * 2);
    unsigned short* Yb   = (unsigned short*)alloc(1024 * 512 * 2);
    unsigned short* QKVb = (unsigned short*)alloc(1024 * 1536 * 2);
    unsigned short* VT   = (unsigned short*)alloc(8L * 64 * 1024 * 2);
    unsigned short* AOb  = (unsigned short*)alloc(1024 * 512 * 2);
    float*          PR   = (float*)alloc(1024 * 512 * 4);
    unsigned short* F1b  = (unsigned short*)alloc(1024L * 2048 * 2);
    float*          F2   = (float*)alloc(1024 * 512 * 4);
    unsigned short* NBb  = (unsigned short*)alloc(1024 * 512 * 2);

    const float* wsrc[10] = {enc_qkv_w, enc_out_w, enc_ff1_w, enc_ff2_w,
                             dec_sa_qkv_w, dec_sa_out_w, dec_ca_qkv_w, dec_ca_out_w,
                             dec_ff1_w, dec_ff2_w};
    const long wper[10] = {1536L*512, 512L*512, 2048L*512, 512L*2048,
                           1536L*512, 512L*512, 1536L*512, 512L*512,
                           2048L*512, 512L*2048};
    long wtot = 0;
    for (int t = 0; t < 10; ++t) wtot += wper[t] * NLAY;

    const size_t used = (size_t)(p - (char*)d_ws);
    const bool preconv = (ws_size > used) && ((ws_size - used) >= (size_t)wtot * 2 + 4096);

    unsigned short* wpre[10] = {};
    unsigned short* slots[2] = {};
    int slot_ctr = 0;
    if (preconv) {
        for (int t = 0; t < 10; ++t) {
            wpre[t] = (unsigned short*)alloc((size_t)wper[t] * NLAY * 2);
            long n = wper[t] * NLAY;
            long blocks = (n / 8 + 255) / 256; if (blocks > 2048) blocks = 2048;
            f2b_k<<<dim3((unsigned)blocks), 256, 0, stream>>>(wsrc[t], wpre[t], n);
        }
    } else {
        slots[0] = (unsigned short*)alloc(2048L * 512 * 2);
        slots[1] = (unsigned short*)alloc(2048L * 512 * 2);
    }
    auto W = [&](int t, int layer) -> const unsigned short* {
        if (preconv) return wpre[t] + (long)layer * wper[t];
        unsigned short* dst = slots[(slot_ctr++) & 1];
        const long n = wper[t];
        long blocks = (n / 8 + 255) / 256; if (blocks > 2048) blocks = 2048;
        f2b_k<<<dim3((unsigned)blocks), 256, 0, stream>>>(wsrc[t] + (long)layer * wper[t], dst, n);
        return dst;
    };

    float* out_gram = (float*)d_out;
    float* out_attn = out_gram + 1024 * 1024;

    auto run_attn = [&](const unsigned short* qb, const unsigned short* kvb,
                        int wt_qkv, int wt_o, int layer,
                        const float* bqkv, const float* bo) {
        if (qb == kvb) {
            gemm4(stream, false, true, qb, 512, 0, W(wt_qkv, layer), 512, 0, bqkv,
                  QKVb, 1536, 0, 1024, 1536, 512, 1.0f, 1, VT, 1024);
        } else {
            const unsigned short* wq = W(wt_qkv, layer);
            gemm4(stream, false, true, qb, 512, 0, wq, 512, 0, bqkv,
                  QKVb, 1536, 0, 1024, 512, 512, 1.0f, 1);
            gemm4(stream, false, true, kvb, 512, 0, wq + 512L * 512, 512, 0, bqkv + 512,
                  QKVb + 512, 1536, 0, 1024, 1024, 512, 1.0f, 1, VT, 512);
        }
        attn_k<<<dim3(16, 8), 256, 0, stream>>>(QKVb, VT, AOb);
        gemm4(stream, false, false, AOb, 512, 0, W(wt_o, layer), 512, 0, bo,
              PR, 512, 0, 1024, 512, 512, 1.0f, 1);
    };

    init_k<<<512, 256, 0, stream>>>(x, MEMf, Yf, MEMb, Yb);

    // ----------------------------- encoder -----------------------------------
    for (int i = 0; i < NLAY; ++i) {
        run_attn(MEMb, MEMb, 0, 1, i, enc_qkv_b + i * 1536, enc_out_b + i * 512);
        ln_k<<<256, 256, 0, stream>>>(MEMf, PR, enc_ln1_s + i * 512, enc_ln1_b + i * 512, MEMf, MEMb);
        gemm4(stream, true,  true,  MEMb, 512, 0, W(2, i), 512, 0, enc_ff1_b + i * 2048,
              F1b, 2048, 0, 1024, 2048, 512, 1.0f, 1);
        gemm4(stream, false, false, F1b, 2048, 0, W(3, i), 2048, 0, enc_ff2_b + i * 512,
              F2, 512, 0, 1024, 512, 2048, 1.0f, 1);
        ln_k<<<256, 256, 0, stream>>>(MEMf, F2, enc_ln2_s + i * 512, enc_ln2_b + i * 512, MEMf, MEMb);
    }
    ln_k<<<256, 256, 0, stream>>>(MEMf, nullptr, enc_norm_s, enc_norm_b, MEMf, MEMb);

    // ----------------------------- decoder -----------------------------------
    for (int i = 0; i < NLAY; ++i) {
        run_attn(Yb, Yb, 4, 5, i, dec_sa_qkv_b + i * 1536, dec_sa_out_b + i * 512);
        ln_k<<<256, 256, 0, stream>>>(Yf, PR, dec_ln1_s + i * 512, dec_ln1_b + i * 512, Yf, Yb);

        run_attn(Yb, MEMb, 6, 7, i, dec_ca_qkv_b + i * 1536, dec_ca_out_b + i * 512);
        ln_k<<<256, 256, 0, stream>>>(Yf, PR, dec_ln2_s + i * 512, dec_ln2_b + i * 512, Yf, Yb);

        gemm4(stream, true,  true,  Yb, 512, 0, W(8, i), 512, 0, dec_ff1_b + i * 2048,
              F1b, 2048, 0, 1024, 2048, 512, 1.0f, 1);
        gemm4(stream, false, false, F1b, 2048, 0, W(9, i), 2048, 0, dec_ff2_b + i * 512,
              F2, 512, 0, 1024, 512, 2048, 1.0f, 1);
        ln_k<<<256, 256, 0, stream>>>(Yf, F2, dec_ln3_s + i * 512, dec_ln3_b + i * 512, Yf, Yb);
    }

    // final: attention_out, n = rownorm, gram = n@n^T
    ln_k<<<256, 256, 0, stream>>>(Yf, nullptr, dec_norm_s, dec_norm_b, out_attn, nullptr);
    l2norm_k<<<256, 256, 0, stream>>>(out_attn, NBb);
    gemm4(stream, false, false, NBb, 512, 0, NBb, 512, 0, nullptr,
          out_gram, 1024, 0, 1024, 1024, 512, 1.0f, 1);
}

// Round 4
// 1513.192 us; speedup vs baseline: 4.4377x; 1.0586x over previous
//
#include <hip/hip_runtime.h>

// MyTransformer: 6-enc + 6-dec, S=1024, D=512, H=8x64, FF=2048.
// Round 3: 4-buf (GEMM) / 3-buf (attn) LDS pipelines with counted vmcnt,
// merged cross-attn QKV dispatch, single-dispatch weight cvt, fused final LN+L2.

#define NLAY 6

typedef __attribute__((ext_vector_type(8))) short short8;
typedef __attribute__((ext_vector_type(4))) short short4v;
typedef __attribute__((ext_vector_type(4))) float f32x4;

typedef __attribute__((address_space(3))) short lds_short;
typedef __attribute__((address_space(1))) const unsigned short g_ushort;

__device__ __forceinline__ void gload16(const unsigned short* g, short* l) {
    __builtin_amdgcn_global_load_lds((g_ushort*)g, (lds_short*)l, 16, 0, 0);
}

__device__ __forceinline__ void waitvm(int n) {   // n in {0,4,8}, wave-uniform
    if (n == 0)      asm volatile("s_waitcnt vmcnt(0)" ::: "memory");
    else if (n == 4) asm volatile("s_waitcnt vmcnt(4)" ::: "memory");
    else             asm volatile("s_waitcnt vmcnt(8)" ::: "memory");
}

__device__ inline unsigned short f2bu(float x) {
    unsigned u = __builtin_bit_cast(unsigned, x);
    unsigned r = (u + 0x7fffu + ((u >> 16) & 1u)) >> 16;   // RNE
    return (unsigned short)r;
}

// ---------------- fp32 -> bf16 conversion: all 10 weight tensors, 1 dispatch --
struct WCvt {
    const float* src[10];
    unsigned short* dst[10];
    long n[10];
};

__global__ __launch_bounds__(256)
void f2ball_k(WCvt wc)
{
    const int t = blockIdx.y;
    const float* s = wc.src[t];
    unsigned short* d = wc.dst[t];
    const long n = wc.n[t];
    const long stride = (long)gridDim.x * 256;
    for (long i = (long)blockIdx.x * 256 + threadIdx.x; i * 8 < n; i += stride) {
        const long o = i * 8;
        const float4 a = *(const float4*)(s + o);
        const float4 b = *(const float4*)(s + o + 4);
        short8 v;
        v[0] = (short)f2bu(a.x); v[1] = (short)f2bu(a.y);
        v[2] = (short)f2bu(a.z); v[3] = (short)f2bu(a.w);
        v[4] = (short)f2bu(b.x); v[5] = (short)f2bu(b.y);
        v[6] = (short)f2bu(b.z); v[7] = (short)f2bu(b.w);
        *(short8*)(d + o) = v;
    }
}

__global__ __launch_bounds__(256)
void f2b_k(const float* __restrict__ s, unsigned short* __restrict__ d, long n)
{
    const long stride = (long)gridDim.x * 256;
    for (long i = (long)blockIdx.x * 256 + threadIdx.x; i * 8 < n; i += stride) {
        const long o = i * 8;
        const float4 a = *(const float4*)(s + o);
        const float4 b = *(const float4*)(s + o + 4);
        short8 v;
        v[0] = (short)f2bu(a.x); v[1] = (short)f2bu(a.y);
        v[2] = (short)f2bu(a.z); v[3] = (short)f2bu(a.w);
        v[4] = (short)f2bu(b.x); v[5] = (short)f2bu(b.y);
        v[6] = (short)f2bu(b.z); v[7] = (short)f2bu(b.w);
        *(short8*)(d + o) = v;
    }
}

// ---------------- 4-wave MFMA GEMM: C = alpha * A @ B^T + bias ---------------
// A: [M][K] bf16 (lda), B: [N][K] bf16 (ldb). 256 thr = 4 waves, tile 64x64,
// wave w owns rows [w*16, w*16+16). BK=64, 4-buffer LDS pipeline via
// global_load_lds (linear dest, pre-swizzled source), prefetch depth 3.
// If A2 != null: blocks with n0 >= a2_col read A2 instead of A (merged QKV).
// If VTp != null: cols n >= vt_col0 also scatter to VTp[h][d][m] (bf16).
template<bool RELU, bool OBF16>
__global__ __launch_bounds__(256)
void gemm4_k(const unsigned short* __restrict__ A,
             const unsigned short* __restrict__ A2, int a2_col,
             int lda, long sA,
             const unsigned short* __restrict__ B, int ldb, long sB,
             const float* __restrict__ bias,
             void* __restrict__ Cv, int ldc, long sC,
             int K, float alpha,
             unsigned short* __restrict__ VTp, int vt_col0)
{
    __shared__ __align__(16) short As[4][64 * 64];   // 32 KB
    __shared__ __align__(16) short Bs[4][64 * 64];   // 32 KB
    const int bz = blockIdx.z;
    const int m0 = blockIdx.y * 64;
    const int n0 = blockIdx.x * 64;
    if (A2 && n0 >= a2_col) A = A2;
    A += (long)bz * sA;  B += (long)bz * sB;
    const int tid = threadIdx.x;
    const int w  = tid >> 6;
    const int l  = tid & 63;
    const int fr = l & 15;
    const int kc = l >> 4;

    f32x4 acc[4] = {};
    const int T = K >> 6;

    auto FILL = [&](int t) {
        const int buf = t & 3;
        const int k0 = t * 64;
        #pragma unroll
        for (int it = 0; it < 2; ++it) {
            const int row = w * 16 + it * 8 + (l >> 3);
            const int sl  = ((l & 7) ^ (row & 7)) * 8;
            gload16(A + (long)(m0 + row) * lda + k0 + sl, &As[buf][(w * 16 + it * 8) * 64]);
            gload16(B + (long)(n0 + row) * ldb + k0 + sl, &Bs[buf][(w * 16 + it * 8) * 64]);
        }
    };

    FILL(0);
    if (1 < T) FILL(1);
    if (2 < T) FILL(2);
    for (int t = 0; t < T; ++t) {
        const int rem = T - 1 - t;
        waitvm(rem >= 2 ? 8 : rem * 4);
        __builtin_amdgcn_sched_barrier(0);
        __builtin_amdgcn_s_barrier();
        if (t + 3 < T) FILL(t + 3);
        const int buf = t & 3;
        #pragma unroll
        for (int ks = 0; ks < 2; ++ks) {
            const int arow = w * 16 + fr;
            const short8 af = *(const short8*)&As[buf][arow * 64 + (((ks * 4 + kc) ^ (arow & 7)) * 8)];
            #pragma unroll
            for (int c = 0; c < 4; ++c) {
                const int brow = c * 16 + fr;
                const short8 bf = *(const short8*)&Bs[buf][brow * 64 + (((ks * 4 + kc) ^ (brow & 7)) * 8)];
                acc[c] = __builtin_amdgcn_mfma_f32_16x16x32_bf16(af, bf, acc[c], 0, 0, 0);
            }
        }
    }

    #pragma unroll
    for (int c = 0; c < 4; ++c) {
        const int n = n0 + c * 16 + fr;
        const float bv = bias ? bias[n] : 0.0f;
        const bool do_vt = (VTp != nullptr) && (n >= vt_col0);
        #pragma unroll
        for (int i = 0; i < 4; ++i) {
            const long m = m0 + w * 16 + kc * 4 + i;
            float v = acc[c][i] * alpha + bv;
            if (RELU) v = fmaxf(v, 0.0f);
            if (OBF16) ((unsigned short*)Cv)[bz * sC + m * ldc + n] = f2bu(v);
            else       ((float*)Cv)[bz * sC + m * ldc + n] = v;
            if (do_vt) {
                const int vc = n - vt_col0;
                VTp[(long)(vc >> 6) * 65536 + (long)(vc & 63) * 1024 + m] = f2bu(v);
            }
        }
    }
}

// ---------------- fused attention: O = softmax(QK^T/8) V ---------------------
// Grid (16 q-tiles, 8 heads), 256 thr = 4 waves; wave w owns q rows
// qt*64+w*16..+16. Q in regs; K (QKVb) and V (VT = [h][d][s]) in a 3-buffer
// LDS pipeline; online softmax in-register; P via wave-private swizzled LDS.
__global__ __launch_bounds__(256)
void attn_k(const unsigned short* __restrict__ QKVb,   // [1024][1536]
            const unsigned short* __restrict__ VT,     // [8][64][1024]
            unsigned short* __restrict__ AOb)          // [1024][512]
{
    __shared__ __align__(16) short Ks[3][64 * 64];     // 24 KB
    __shared__ __align__(16) short Vs[3][64 * 64];     // 24 KB
    __shared__ __align__(16) short Ps[4][16 * 64];     // 8 KB
    const int qt = blockIdx.x;
    const int h  = blockIdx.y;
    const int tid = threadIdx.x;
    const int w  = tid >> 6;
    const int l  = tid & 63;
    const int fr = l & 15;
    const int kc = l >> 4;

    const int qrow = qt * 64 + w * 16 + fr;
    short8 qf[2];
    qf[0] = *(const short8*)(QKVb + (long)qrow * 1536 + h * 64 + kc * 8);
    qf[1] = *(const short8*)(QKVb + (long)qrow * 1536 + h * 64 + 32 + kc * 8);

    auto FILL = [&](int t, int buf) {
        const int kb = t * 64;
        #pragma unroll
        for (int it = 0; it < 2; ++it) {
            const int row = w * 16 + it * 8 + (l >> 3);
            const int sl  = ((l & 7) ^ (row & 7)) * 8;
            gload16(QKVb + (long)(kb + row) * 1536 + 512 + h * 64 + sl,
                    &Ks[buf][(w * 16 + it * 8) * 64]);
            gload16(VT + (long)h * 65536 + (long)row * 1024 + kb + sl,
                    &Vs[buf][(w * 16 + it * 8) * 64]);
        }
    };

    float m_i[4], l_i[4];
    f32x4 acc_o[4] = {};
    #pragma unroll
    for (int i = 0; i < 4; ++i) { m_i[i] = -1e30f; l_i[i] = 0.f; }

    short* ps = &Ps[w][0];

    FILL(0, 0); FILL(1, 1);
    int fb = 2, cb = 0;
    for (int t = 0; t < 16; ++t) {
        waitvm(t == 15 ? 0 : 4);
        __builtin_amdgcn_sched_barrier(0);
        __builtin_amdgcn_s_barrier();
        if (t + 2 < 16) { FILL(t + 2, fb); fb = (fb == 2) ? 0 : fb + 1; }

        // S = Q @ K^T
        f32x4 sacc[4] = {};
        #pragma unroll
        for (int ks = 0; ks < 2; ++ks) {
            #pragma unroll
            for (int c = 0; c < 4; ++c) {
                const int krow = c * 16 + fr;
                const short8 kf = *(const short8*)&Ks[cb][krow * 64 + (((ks * 4 + kc) ^ (krow & 7)) * 8)];
                sacc[c] = __builtin_amdgcn_mfma_f32_16x16x32_bf16(qf[ks], kf, sacc[c], 0, 0, 0);
            }
        }

        // online softmax (scale 1/8); rows lane-local per 16-lane group
        float p[4][4];
        #pragma unroll
        for (int i = 0; i < 4; ++i) {
            float tm = fmaxf(fmaxf(sacc[0][i], sacc[1][i]), fmaxf(sacc[2][i], sacc[3][i]));
            #pragma unroll
            for (int off = 8; off; off >>= 1) tm = fmaxf(tm, __shfl_xor(tm, off));
            tm *= 0.125f;
            const float mn = fmaxf(m_i[i], tm);
            const float sc = __expf(m_i[i] - mn);
            m_i[i] = mn;
            float ts = 0.f;
            #pragma unroll
            for (int c = 0; c < 4; ++c) { p[c][i] = __expf(sacc[c][i] * 0.125f - mn); ts += p[c][i]; }
            #pragma unroll
            for (int off = 8; off; off >>= 1) ts += __shfl_xor(ts, off);
            l_i[i] = l_i[i] * sc + ts;
            #pragma unroll
            for (int c = 0; c < 4; ++c) acc_o[c][i] *= sc;
        }

        // P -> wave-private LDS (bf16, swizzled at 8-elem granularity)
        #pragma unroll
        for (int c = 0; c < 4; ++c) {
            const int col = c * 16 + fr;
            #pragma unroll
            for (int i = 0; i < 4; ++i) {
                const int row = kc * 4 + i;
                ps[row * 64 + (((col >> 3) ^ (row & 7)) * 8) + (col & 7)] = (short)f2bu(p[c][i]);
            }
        }
        short8 pf[2];
        pf[0] = *(const short8*)&ps[fr * 64 + ((kc ^ (fr & 7)) * 8)];
        pf[1] = *(const short8*)&ps[fr * 64 + (((4 + kc) ^ (fr & 7)) * 8)];

        // O += P @ V
        #pragma unroll
        for (int ks = 0; ks < 2; ++ks) {
            #pragma unroll
            for (int c = 0; c < 4; ++c) {
                const int drow = c * 16 + fr;
                const short8 vf = *(const short8*)&Vs[cb][drow * 64 + (((ks * 4 + kc) ^ (drow & 7)) * 8)];
                acc_o[c] = __builtin_amdgcn_mfma_f32_16x16x32_bf16(pf[ks], vf, acc_o[c], 0, 0, 0);
            }
        }
        cb = (cb == 2) ? 0 : cb + 1;
    }

    #pragma unroll
    for (int c = 0; c < 4; ++c) {
        const int dcol = h * 64 + c * 16 + fr;
        #pragma unroll
        for (int i = 0; i < 4; ++i) {
            const int row = qt * 64 + w * 16 + kc * 4 + i;
            AOb[(long)row * 512 + dcol] = f2bu(acc_o[c][i] / l_i[i]);
        }
    }
}

// -------- LayerNorm rows of 512: out fp32 (+ optional bf16 copy) -------------
__global__ __launch_bounds__(256)
void ln_k(const float* __restrict__ x, const float* __restrict__ a,
          const float* __restrict__ s, const float* __restrict__ b,
          float* __restrict__ out, unsigned short* __restrict__ outb)
{
    const int lane = threadIdx.x & 63;
    const int row  = (blockIdx.x << 2) + (threadIdx.x >> 6);
    const float* px = x + (long)row * 512;
    float v[8];
    float sum = 0.f;
    #pragma unroll
    for (int i = 0; i < 8; ++i) {
        v[i] = px[lane + (i << 6)];
        if (a) v[i] += a[(long)row * 512 + lane + (i << 6)];
        sum += v[i];
    }
    #pragma unroll
    for (int off = 32; off; off >>= 1) sum += __shfl_xor(sum, off);
    const float m = sum * (1.0f / 512.0f);
    float s2 = 0.f;
    #pragma unroll
    for (int i = 0; i < 8; ++i) { const float d = v[i] - m; s2 += d * d; }
    #pragma unroll
    for (int off = 32; off; off >>= 1) s2 += __shfl_xor(s2, off);
    const float inv = rsqrtf(s2 * (1.0f / 512.0f) + 1e-5f);
    #pragma unroll
    for (int i = 0; i < 8; ++i) {
        const int j = lane + (i << 6);
        const float r = (v[i] - m) * inv * s[j] + b[j];
        out[(long)row * 512 + j] = r;
        if (outb) outb[(long)row * 512 + j] = f2bu(r);
    }
}

// -------- fused final LN + L2-normalize ------------------------------------
// r = LN(x)*s+b -> out_attn (fp32); nb = r/||r|| (bf16)
__global__ __launch_bounds__(256)
void lnl2_k(const float* __restrict__ x,
            const float* __restrict__ s, const float* __restrict__ b,
            float* __restrict__ out_attn, unsigned short* __restrict__ nb)
{
    const int lane = threadIdx.x & 63;
    const int row  = (blockIdx.x << 2) + (threadIdx.x >> 6);
    const float* px = x + (long)row * 512;
    float v[8];
    float sum = 0.f;
    #pragma unroll
    for (int i = 0; i < 8; ++i) { v[i] = px[lane + (i << 6)]; sum += v[i]; }
    #pragma unroll
    for (int off = 32; off; off >>= 1) sum += __shfl_xor(sum, off);
    const float m = sum * (1.0f / 512.0f);
    float s2 = 0.f;
    #pragma unroll
    for (int i = 0; i < 8; ++i) { const float d = v[i] - m; s2 += d * d; }
    #pragma unroll
    for (int off = 32; off; off >>= 1) s2 += __shfl_xor(s2, off);
    const float inv = rsqrtf(s2 * (1.0f / 512.0f) + 1e-5f);
    float nrm = 0.f;
    #pragma unroll
    for (int i = 0; i < 8; ++i) {
        const int j = lane + (i << 6);
        v[i] = (v[i] - m) * inv * s[j] + b[j];
        out_attn[(long)row * 512 + j] = v[i];
        nrm += v[i] * v[i];
    }
    #pragma unroll
    for (int off = 32; off; off >>= 1) nrm += __shfl_xor(nrm, off);
    const float rinv = rsqrtf(nrm);
    #pragma unroll
    for (int i = 0; i < 8; ++i)
        nb[(long)row * 512 + lane + (i << 6)] = f2bu(v[i] * rinv);
}

// -------- init: x -> MEMf, Yf (fp32) + MEMb, Yb (bf16) -----------------------
__global__ __launch_bounds__(256)
void init_k(const float* __restrict__ x, float* __restrict__ mf, float* __restrict__ yf,
            unsigned short* __restrict__ mb, unsigned short* __restrict__ yb)
{
    const long i = ((long)blockIdx.x * 256 + threadIdx.x) * 4;
    const float4 v = *(const float4*)(x + i);
    *(float4*)(mf + i) = v;
    *(float4*)(yf + i) = v;
    short4v s;
    s[0] = (short)f2bu(v.x); s[1] = (short)f2bu(v.y);
    s[2] = (short)f2bu(v.z); s[3] = (short)f2bu(v.w);
    *(short4v*)(mb + i) = s;
    *(short4v*)(yb + i) = s;
}

// ------------------------------ host side ------------------------------------
static void gemm4(hipStream_t st, bool relu, bool obf16,
                  const unsigned short* A, int lda, long sA,
                  const unsigned short* B, int ldb, long sB,
                  const float* bias, void* C, int ldc, long sC,
                  int M, int N, int K, float alpha, int batch,
                  unsigned short* VTp = nullptr, int vt_col0 = 0,
                  const unsigned short* A2 = nullptr, int a2_col = 0)
{
    dim3 g(N / 64, M / 64, batch);
    if (obf16) {
        if (relu) gemm4_k<true,  true ><<<g, 256, 0, st>>>(A, A2, a2_col, lda, sA, B, ldb, sB, bias, C, ldc, sC, K, alpha, VTp, vt_col0);
        else      gemm4_k<false, true ><<<g, 256, 0, st>>>(A, A2, a2_col, lda, sA, B, ldb, sB, bias, C, ldc, sC, K, alpha, VTp, vt_col0);
    } else {
        if (relu) gemm4_k<true,  false><<<g, 256, 0, st>>>(A, A2, a2_col, lda, sA, B, ldb, sB, bias, C, ldc, sC, K, alpha, VTp, vt_col0);
        else      gemm4_k<false, false><<<g, 256, 0, st>>>(A, A2, a2_col, lda, sA, B, ldb, sB, bias, C, ldc, sC, K, alpha, VTp, vt_col0);
    }
}

extern "C" void kernel_launch(void* const* d_in, const int* in_sizes, int n_in,
                              void* d_out, int out_size, void* d_ws, size_t ws_size,
                              hipStream_t stream)
{
    const float* x            = (const float*)d_in[0];
    const float* enc_qkv_w    = (const float*)d_in[1];
    const float* enc_qkv_b    = (const float*)d_in[2];
    const float* enc_out_w    = (const float*)d_in[3];
    const float* enc_out_b    = (const float*)d_in[4];
    const float* enc_ff1_w    = (const float*)d_in[5];
    const float* enc_ff1_b    = (const float*)d_in[6];
    const float* enc_ff2_w    = (const float*)d_in[7];
    const float* enc_ff2_b    = (const float*)d_in[8];
    const float* enc_ln1_s    = (const float*)d_in[9];
    const float* enc_ln1_b    = (const float*)d_in[10];
    const float* enc_ln2_s    = (const float*)d_in[11];
    const float* enc_ln2_b    = (const float*)d_in[12];
    const float* dec_sa_qkv_w = (const float*)d_in[13];
    const float* dec_sa_qkv_b = (const float*)d_in[14];
    const float* dec_sa_out_w = (const float*)d_in[15];
    const float* dec_sa_out_b = (const float*)d_in[16];
    const float* dec_ca_qkv_w = (const float*)d_in[17];
    const float* dec_ca_qkv_b = (const float*)d_in[18];
    const float* dec_ca_out_w = (const float*)d_in[19];
    const float* dec_ca_out_b = (const float*)d_in[20];
    const float* dec_ff1_w    = (const float*)d_in[21];
    const float* dec_ff1_b    = (const float*)d_in[22];
    const float* dec_ff2_w    = (const float*)d_in[23];
    const float* dec_ff2_b    = (const float*)d_in[24];
    const float* dec_ln1_s    = (const float*)d_in[25];
    const float* dec_ln1_b    = (const float*)d_in[26];
    const float* dec_ln2_s    = (const float*)d_in[27];
    const float* dec_ln2_b    = (const float*)d_in[28];
    const float* dec_ln3_s    = (const float*)d_in[29];
    const float* dec_ln3_b    = (const float*)d_in[30];
    const float* enc_norm_s   = (const float*)d_in[31];
    const float* enc_norm_b   = (const float*)d_in[32];
    const float* dec_norm_s   = (const float*)d_in[33];
    const float* dec_norm_b   = (const float*)d_in[34];

    char* p = (char*)d_ws;
    auto alloc = [&](size_t bytes) -> char* {
        char* r = p; p += (bytes + 255) & ~(size_t)255; return r;
    };
    float*          MEMf = (float*)alloc(1024 * 512 * 4);
    float*          Yf   = (float*)alloc(1024 * 512 * 4);
    unsigned short* MEMb = (unsigned short*)alloc(1024 * 512 * 2);
    unsigned short* Yb   = (unsigned short*)alloc(1024 * 512 * 2);
    unsigned short* QKVb = (unsigned short*)alloc(1024 * 1536 * 2);
    unsigned short* VT   = (unsigned short*)alloc(8L * 64 * 1024 * 2);
    unsigned short* AOb  = (unsigned short*)alloc(1024 * 512 * 2);
    float*          PR   = (float*)alloc(1024 * 512 * 4);
    unsigned short* F1b  = (unsigned short*)alloc(1024L * 2048 * 2);
    float*          F2   = (float*)alloc(1024 * 512 * 4);
    unsigned short* NBb  = (unsigned short*)alloc(1024 * 512 * 2);

    const float* wsrc[10] = {enc_qkv_w, enc_out_w, enc_ff1_w, enc_ff2_w,
                             dec_sa_qkv_w, dec_sa_out_w, dec_ca_qkv_w, dec_ca_out_w,
                             dec_ff1_w, dec_ff2_w};
    const long wper[10] = {1536L*512, 512L*512, 2048L*512, 512L*2048,
                           1536L*512, 512L*512, 1536L*512, 512L*512,
                           2048L*512, 512L*2048};
    long wtot = 0;
    for (int t = 0; t < 10; ++t) wtot += wper[t] * NLAY;

    const size_t used = (size_t)(p - (char*)d_ws);
    const bool preconv = (ws_size > used) && ((ws_size - used) >= (size_t)wtot * 2 + 4096);

    unsigned short* wpre[10] = {};
    unsigned short* slots[2] = {};
    int slot_ctr = 0;
    if (preconv) {
        WCvt wc;
        for (int t = 0; t < 10; ++t) {
            wpre[t] = (unsigned short*)alloc((size_t)wper[t] * NLAY * 2);
            wc.src[t] = wsrc[t];
            wc.dst[t] = wpre[t];
            wc.n[t]   = wper[t] * NLAY;
        }
        f2ball_k<<<dim3(128, 10), 256, 0, stream>>>(wc);
    } else {
        slots[0] = (unsigned short*)alloc(2048L * 512 * 2);
        slots[1] = (unsigned short*)alloc(2048L * 512 * 2);
    }
    auto W = [&](int t, int layer) -> const unsigned short* {
        if (preconv) return wpre[t] + (long)layer * wper[t];
        unsigned short* dst = slots[(slot_ctr++) & 1];
        const long n = wper[t];
        long blocks = (n / 8 + 255) / 256; if (blocks > 2048) blocks = 2048;
        f2b_k<<<dim3((unsigned)blocks), 256, 0, stream>>>(wsrc[t] + (long)layer * wper[t], dst, n);
        return dst;
    };

    float* out_gram = (float*)d_out;
    float* out_attn = out_gram + 1024 * 1024;

    // attention block: merged QKV (q cols 0-511 from qb, kv cols 512-1535 from kvb)
    auto run_attn = [&](const unsigned short* qb, const unsigned short* kvb,
                        int wt_qkv, int wt_o, int layer,
                        const float* bqkv, const float* bo) {
        gemm4(stream, false, true, qb, 512, 0, W(wt_qkv, layer), 512, 0, bqkv,
              QKVb, 1536, 0, 1024, 1536, 512, 1.0f, 1, VT, 1024,
              (qb == kvb) ? nullptr : kvb, 512);
        attn_k<<<dim3(16, 8), 256, 0, stream>>>(QKVb, VT, AOb);
        gemm4(stream, false, false, AOb, 512, 0, W(wt_o, layer), 512, 0, bo,
              PR, 512, 0, 1024, 512, 512, 1.0f, 1);
    };

    init_k<<<512, 256, 0, stream>>>(x, MEMf, Yf, MEMb, Yb);

    // ----------------------------- encoder -----------------------------------
    for (int i = 0; i < NLAY; ++i) {
        run_attn(MEMb, MEMb, 0, 1, i, enc_qkv_b + i * 1536, enc_out_b + i * 512);
        ln_k<<<256, 256, 0, stream>>>(MEMf, PR, enc_ln1_s + i * 512, enc_ln1_b + i * 512, MEMf, MEMb);
        gemm4(stream, true,  true,  MEMb, 512, 0, W(2, i), 512, 0, enc_ff1_b + i * 2048,
              F1b, 2048, 0, 1024, 2048, 512, 1.0f, 1);
        gemm4(stream, false, false, F1b, 2048, 0, W(3, i), 2048, 0, enc_ff2_b + i * 512,
              F2, 512, 0, 1024, 512, 2048, 1.0f, 1);
        ln_k<<<256, 256, 0, stream>>>(MEMf, F2, enc_ln2_s + i * 512, enc_ln2_b + i * 512, MEMf, MEMb);
    }
    ln_k<<<256, 256, 0, stream>>>(MEMf, nullptr, enc_norm_s, enc_norm_b, MEMf, MEMb);

    // ----------------------------- decoder -----------------------------------
    for (int i = 0; i < NLAY; ++i) {
        run_attn(Yb, Yb, 4, 5, i, dec_sa_qkv_b + i * 1536, dec_sa_out_b + i * 512);
        ln_k<<<256, 256, 0, stream>>>(Yf, PR, dec_ln1_s + i * 512, dec_ln1_b + i * 512, Yf, Yb);

        run_attn(Yb, MEMb, 6, 7, i, dec_ca_qkv_b + i * 1536, dec_ca_out_b + i * 512);
        ln_k<<<256, 256, 0, stream>>>(Yf, PR, dec_ln2_s + i * 512, dec_ln2_b + i * 512, Yf, Yb);

        gemm4(stream, true,  true,  Yb, 512, 0, W(8, i), 512, 0, dec_ff1_b + i * 2048,
              F1b, 2048, 0, 1024, 2048, 512, 1.0f, 1);
        gemm4(stream, false, false, F1b, 2048, 0, W(9, i), 2048, 0, dec_ff2_b + i * 512,
              F2, 512, 0, 1024, 512, 2048, 1.0f, 1);
        ln_k<<<256, 256, 0, stream>>>(Yf, F2, dec_ln3_s + i * 512, dec_ln3_b + i * 512, Yf, Yb);
    }

    // final: attention_out + n = rownorm (fused), gram = n@n^T
    lnl2_k<<<256, 256, 0, stream>>>(Yf, dec_norm_s, dec_norm_b, out_attn, NBb);
    gemm4(stream, false, false, NBb, 512, 0, NBb, 512, 0, nullptr,
          out_gram, 1024, 0, 1024, 1024, 512, 1.0f, 1);
}

// Round 5
// 1464.867 us; speedup vs baseline: 4.5841x; 1.0330x over previous
//
#include <hip/hip_runtime.h>

// MyTransformer: 6-enc + 6-dec, S=1024, D=512, H=8x64, FF=2048.
// Round 4: balanced flat-grid weight cvt; split-K slab GEMMs for FF2(x4)/proj(x2)
// with LN-as-merge (bias folded into LN); attention q-tiles 32 (256 blocks).

#define NLAY 6

typedef __attribute__((ext_vector_type(8))) short short8;
typedef __attribute__((ext_vector_type(4))) short short4v;
typedef __attribute__((ext_vector_type(4))) float f32x4;

typedef __attribute__((address_space(3))) short lds_short;
typedef __attribute__((address_space(1))) const unsigned short g_ushort;

__device__ __forceinline__ void gload16(const unsigned short* g, short* l) {
    __builtin_amdgcn_global_load_lds((g_ushort*)g, (lds_short*)l, 16, 0, 0);
}

__device__ __forceinline__ void waitvm(int n) {   // n in {0,4,8}, wave-uniform
    if (n == 0)      asm volatile("s_waitcnt vmcnt(0)" ::: "memory");
    else if (n == 4) asm volatile("s_waitcnt vmcnt(4)" ::: "memory");
    else             asm volatile("s_waitcnt vmcnt(8)" ::: "memory");
}

__device__ inline unsigned short f2bu(float x) {
    unsigned u = __builtin_bit_cast(unsigned, x);
    unsigned r = (u + 0x7fffu + ((u >> 16) & 1u)) >> 16;   // RNE
    return (unsigned short)r;
}

// ------------- fp32 -> bf16 weight cvt: flat balanced grid, 1 dispatch -------
struct WCvt {
    const float* src[10];
    unsigned short* dst[10];
    long cum[11];           // prefix sums in 8-element chunks
};

__global__ __launch_bounds__(256)
void f2ball_k(WCvt wc)
{
    const long total = wc.cum[10];
    for (long c = (long)blockIdx.x * 256 + threadIdx.x; c < total;
         c += (long)gridDim.x * 256) {
        int t = 0;
        #pragma unroll
        for (int i = 1; i < 10; ++i) if (c >= wc.cum[i]) t = i;
        const long o = (c - wc.cum[t]) * 8;
        const float* s = wc.src[t];
        unsigned short* d = wc.dst[t];
        const float4 a = *(const float4*)(s + o);
        const float4 b = *(const float4*)(s + o + 4);
        short8 v;
        v[0] = (short)f2bu(a.x); v[1] = (short)f2bu(a.y);
        v[2] = (short)f2bu(a.z); v[3] = (short)f2bu(a.w);
        v[4] = (short)f2bu(b.x); v[5] = (short)f2bu(b.y);
        v[6] = (short)f2bu(b.z); v[7] = (short)f2bu(b.w);
        *(short8*)(d + o) = v;
    }
}

__global__ __launch_bounds__(256)
void f2b_k(const float* __restrict__ s, unsigned short* __restrict__ d, long n)
{
    const long stride = (long)gridDim.x * 256;
    for (long i = (long)blockIdx.x * 256 + threadIdx.x; i * 8 < n; i += stride) {
        const long o = i * 8;
        const float4 a = *(const float4*)(s + o);
        const float4 b = *(const float4*)(s + o + 4);
        short8 v;
        v[0] = (short)f2bu(a.x); v[1] = (short)f2bu(a.y);
        v[2] = (short)f2bu(a.z); v[3] = (short)f2bu(a.w);
        v[4] = (short)f2bu(b.x); v[5] = (short)f2bu(b.y);
        v[6] = (short)f2bu(b.z); v[7] = (short)f2bu(b.w);
        *(short8*)(d + o) = v;
    }
}

// ---------------- 4-wave MFMA GEMM: C = alpha * A @ B^T + bias ---------------
// A: [M][K] bf16 (lda), B: [N][K] bf16 (ldb). 256 thr = 4 waves, tile 64x64,
// wave w owns rows [w*16, w*16+16). BK=64, 4-buffer LDS pipeline via
// global_load_lds, prefetch depth 3. Per-z: A/B element offset += z*kz
// (split-K), C += z*sC (slab). If A2: blocks with n0 >= a2_col read A2.
// If VTp: cols n >= vt_col0 also scatter to VTp[h][d][m] (bf16).
template<bool RELU, bool OBF16>
__global__ __launch_bounds__(256)
void gemm4_k(const unsigned short* __restrict__ A,
             const unsigned short* __restrict__ A2, int a2_col,
             int lda, long sA,
             const unsigned short* __restrict__ B, int ldb, long sB,
             const float* __restrict__ bias,
             void* __restrict__ Cv, int ldc, long sC,
             int K, float alpha,
             unsigned short* __restrict__ VTp, int vt_col0, int kz)
{
    __shared__ __align__(16) short As[4][64 * 64];   // 32 KB
    __shared__ __align__(16) short Bs[4][64 * 64];   // 32 KB
    const int bz = blockIdx.z;
    const int m0 = blockIdx.y * 64;
    const int n0 = blockIdx.x * 64;
    if (A2 && n0 >= a2_col) A = A2;
    A += (long)bz * sA + (long)bz * kz;
    B += (long)bz * sB + (long)bz * kz;
    const int tid = threadIdx.x;
    const int w  = tid >> 6;
    const int l  = tid & 63;
    const int fr = l & 15;
    const int kc = l >> 4;

    f32x4 acc[4] = {};
    const int T = K >> 6;

    auto FILL = [&](int t) {
        const int buf = t & 3;
        const int k0 = t * 64;
        #pragma unroll
        for (int it = 0; it < 2; ++it) {
            const int row = w * 16 + it * 8 + (l >> 3);
            const int sl  = ((l & 7) ^ (row & 7)) * 8;
            gload16(A + (long)(m0 + row) * lda + k0 + sl, &As[buf][(w * 16 + it * 8) * 64]);
            gload16(B + (long)(n0 + row) * ldb + k0 + sl, &Bs[buf][(w * 16 + it * 8) * 64]);
        }
    };

    FILL(0);
    if (1 < T) FILL(1);
    if (2 < T) FILL(2);
    for (int t = 0; t < T; ++t) {
        const int rem = T - 1 - t;
        waitvm(rem >= 2 ? 8 : rem * 4);
        __builtin_amdgcn_sched_barrier(0);
        __builtin_amdgcn_s_barrier();
        if (t + 3 < T) FILL(t + 3);
        const int buf = t & 3;
        #pragma unroll
        for (int ks = 0; ks < 2; ++ks) {
            const int arow = w * 16 + fr;
            const short8 af = *(const short8*)&As[buf][arow * 64 + (((ks * 4 + kc) ^ (arow & 7)) * 8)];
            #pragma unroll
            for (int c = 0; c < 4; ++c) {
                const int brow = c * 16 + fr;
                const short8 bf = *(const short8*)&Bs[buf][brow * 64 + (((ks * 4 + kc) ^ (brow & 7)) * 8)];
                acc[c] = __builtin_amdgcn_mfma_f32_16x16x32_bf16(af, bf, acc[c], 0, 0, 0);
            }
        }
    }

    #pragma unroll
    for (int c = 0; c < 4; ++c) {
        const int n = n0 + c * 16 + fr;
        const float bv = bias ? bias[n] : 0.0f;
        const bool do_vt = (VTp != nullptr) && (n >= vt_col0);
        #pragma unroll
        for (int i = 0; i < 4; ++i) {
            const long m = m0 + w * 16 + kc * 4 + i;
            float v = acc[c][i] * alpha + bv;
            if (RELU) v = fmaxf(v, 0.0f);
            if (OBF16) ((unsigned short*)Cv)[bz * sC + m * ldc + n] = f2bu(v);
            else       ((float*)Cv)[bz * sC + m * ldc + n] = v;
            if (do_vt) {
                const int vc = n - vt_col0;
                VTp[(long)(vc >> 6) * 65536 + (long)(vc & 63) * 1024 + m] = f2bu(v);
            }
        }
    }
}

// ---------------- fused attention: O = softmax(QK^T/8) V ---------------------
// Grid (32 q-tiles of 32 rows, 8 heads), 128 thr = 2 waves; wave w owns q rows
// qt*32+w*16..+16. Q in regs; K (QKVb) and V (VT=[h][d][s]) in a 3-buffer
// LDS pipeline; online softmax in-register; P via wave-private swizzled LDS.
__global__ __launch_bounds__(128)
void attn_k(const unsigned short* __restrict__ QKVb,   // [1024][1536]
            const unsigned short* __restrict__ VT,     // [8][64][1024]
            unsigned short* __restrict__ AOb)          // [1024][512]
{
    __shared__ __align__(16) short Ks[3][64 * 64];     // 24 KB
    __shared__ __align__(16) short Vs[3][64 * 64];     // 24 KB
    __shared__ __align__(16) short Ps[2][16 * 64];     // 4 KB
    const int qt = blockIdx.x;
    const int h  = blockIdx.y;
    const int tid = threadIdx.x;
    const int w  = tid >> 6;      // 0..1
    const int l  = tid & 63;
    const int fr = l & 15;
    const int kc = l >> 4;

    const int qrow = qt * 32 + w * 16 + fr;
    short8 qf[2];
    qf[0] = *(const short8*)(QKVb + (long)qrow * 1536 + h * 64 + kc * 8);
    qf[1] = *(const short8*)(QKVb + (long)qrow * 1536 + h * 64 + 32 + kc * 8);

    // 2 waves cover the 64-row K/V tiles: 4 groups of 8 rows per wave
    auto FILL = [&](int t, int buf) {
        const int kb = t * 64;
        #pragma unroll
        for (int it = 0; it < 4; ++it) {
            const int row = it * 16 + w * 8 + (l >> 3);
            const int sl  = ((l & 7) ^ (row & 7)) * 8;
            gload16(QKVb + (long)(kb + row) * 1536 + 512 + h * 64 + sl,
                    &Ks[buf][(it * 16 + w * 8) * 64]);
            gload16(VT + (long)h * 65536 + (long)row * 1024 + kb + sl,
                    &Vs[buf][(it * 16 + w * 8) * 64]);
        }
    };

    float m_i[4], l_i[4];
    f32x4 acc_o[4] = {};
    #pragma unroll
    for (int i = 0; i < 4; ++i) { m_i[i] = -1e30f; l_i[i] = 0.f; }

    short* ps = &Ps[w][0];

    FILL(0, 0); FILL(1, 1);
    int fb = 2, cb = 0;
    for (int t = 0; t < 16; ++t) {
        waitvm(t == 15 ? 0 : 8);
        __builtin_amdgcn_sched_barrier(0);
        __builtin_amdgcn_s_barrier();
        if (t + 2 < 16) { FILL(t + 2, fb); fb = (fb == 2) ? 0 : fb + 1; }

        // S = Q @ K^T
        f32x4 sacc[4] = {};
        #pragma unroll
        for (int ks = 0; ks < 2; ++ks) {
            #pragma unroll
            for (int c = 0; c < 4; ++c) {
                const int krow = c * 16 + fr;
                const short8 kf = *(const short8*)&Ks[cb][krow * 64 + (((ks * 4 + kc) ^ (krow & 7)) * 8)];
                sacc[c] = __builtin_amdgcn_mfma_f32_16x16x32_bf16(qf[ks], kf, sacc[c], 0, 0, 0);
            }
        }

        // online softmax (scale 1/8); rows lane-local per 16-lane group
        float p[4][4];
        #pragma unroll
        for (int i = 0; i < 4; ++i) {
            float tm = fmaxf(fmaxf(sacc[0][i], sacc[1][i]), fmaxf(sacc[2][i], sacc[3][i]));
            #pragma unroll
            for (int off = 8; off; off >>= 1) tm = fmaxf(tm, __shfl_xor(tm, off));
            tm *= 0.125f;
            const float mn = fmaxf(m_i[i], tm);
            const float sc = __expf(m_i[i] - mn);
            m_i[i] = mn;
            float ts = 0.f;
            #pragma unroll
            for (int c = 0; c < 4; ++c) { p[c][i] = __expf(sacc[c][i] * 0.125f - mn); ts += p[c][i]; }
            #pragma unroll
            for (int off = 8; off; off >>= 1) ts += __shfl_xor(ts, off);
            l_i[i] = l_i[i] * sc + ts;
            #pragma unroll
            for (int c = 0; c < 4; ++c) acc_o[c][i] *= sc;
        }

        // P -> wave-private LDS (bf16, swizzled at 8-elem granularity)
        #pragma unroll
        for (int c = 0; c < 4; ++c) {
            const int col = c * 16 + fr;
            #pragma unroll
            for (int i = 0; i < 4; ++i) {
                const int row = kc * 4 + i;
                ps[row * 64 + (((col >> 3) ^ (row & 7)) * 8) + (col & 7)] = (short)f2bu(p[c][i]);
            }
        }
        short8 pf[2];
        pf[0] = *(const short8*)&ps[fr * 64 + ((kc ^ (fr & 7)) * 8)];
        pf[1] = *(const short8*)&ps[fr * 64 + (((4 + kc) ^ (fr & 7)) * 8)];

        // O += P @ V
        #pragma unroll
        for (int ks = 0; ks < 2; ++ks) {
            #pragma unroll
            for (int c = 0; c < 4; ++c) {
                const int drow = c * 16 + fr;
                const short8 vf = *(const short8*)&Vs[cb][drow * 64 + (((ks * 4 + kc) ^ (drow & 7)) * 8)];
                acc_o[c] = __builtin_amdgcn_mfma_f32_16x16x32_bf16(pf[ks], vf, acc_o[c], 0, 0, 0);
            }
        }
        cb = (cb == 2) ? 0 : cb + 1;
    }

    #pragma unroll
    for (int c = 0; c < 4; ++c) {
        const int dcol = h * 64 + c * 16 + fr;
        #pragma unroll
        for (int i = 0; i < 4; ++i) {
            const int row = qt * 32 + w * 16 + kc * 4 + i;
            AOb[(long)row * 512 + dcol] = f2bu(acc_o[c][i] / l_i[i]);
        }
    }
}

// -------- LayerNorm-as-merge: out = LN(x + sum_slabs + bias)*s + b -----------
// nslab in {0,2,4}; slab t at slab + t*524288 (fp32 [1024][512]); bias opt.
__global__ __launch_bounds__(256)
void ln_k(const float* __restrict__ x, const float* __restrict__ slab, int nslab,
          const float* __restrict__ bias,
          const float* __restrict__ s, const float* __restrict__ b,
          float* __restrict__ out, unsigned short* __restrict__ outb)
{
    const int lane = threadIdx.x & 63;
    const int row  = (blockIdx.x << 2) + (threadIdx.x >> 6);
    const float* px = x + (long)row * 512;
    float v[8];
    float sum = 0.f;
    #pragma unroll
    for (int i = 0; i < 8; ++i) {
        const int j = lane + (i << 6);
        v[i] = px[j];
        for (int t = 0; t < nslab; ++t) v[i] += slab[(long)t * 524288 + (long)row * 512 + j];
        if (bias) v[i] += bias[j];
        sum += v[i];
    }
    #pragma unroll
    for (int off = 32; off; off >>= 1) sum += __shfl_xor(sum, off);
    const float m = sum * (1.0f / 512.0f);
    float s2 = 0.f;
    #pragma unroll
    for (int i = 0; i < 8; ++i) { const float d = v[i] - m; s2 += d * d; }
    #pragma unroll
    for (int off = 32; off; off >>= 1) s2 += __shfl_xor(s2, off);
    const float inv = rsqrtf(s2 * (1.0f / 512.0f) + 1e-5f);
    #pragma unroll
    for (int i = 0; i < 8; ++i) {
        const int j = lane + (i << 6);
        const float r = (v[i] - m) * inv * s[j] + b[j];
        out[(long)row * 512 + j] = r;
        if (outb) outb[(long)row * 512 + j] = f2bu(r);
    }
}

// -------- fused final LN + L2-normalize --------------------------------------
__global__ __launch_bounds__(256)
void lnl2_k(const float* __restrict__ x,
            const float* __restrict__ s, const float* __restrict__ b,
            float* __restrict__ out_attn, unsigned short* __restrict__ nb)
{
    const int lane = threadIdx.x & 63;
    const int row  = (blockIdx.x << 2) + (threadIdx.x >> 6);
    const float* px = x + (long)row * 512;
    float v[8];
    float sum = 0.f;
    #pragma unroll
    for (int i = 0; i < 8; ++i) { v[i] = px[lane + (i << 6)]; sum += v[i]; }
    #pragma unroll
    for (int off = 32; off; off >>= 1) sum += __shfl_xor(sum, off);
    const float m = sum * (1.0f / 512.0f);
    float s2 = 0.f;
    #pragma unroll
    for (int i = 0; i < 8; ++i) { const float d = v[i] - m; s2 += d * d; }
    #pragma unroll
    for (int off = 32; off; off >>= 1) s2 += __shfl_xor(s2, off);
    const float inv = rsqrtf(s2 * (1.0f / 512.0f) + 1e-5f);
    float nrm = 0.f;
    #pragma unroll
    for (int i = 0; i < 8; ++i) {
        const int j = lane + (i << 6);
        v[i] = (v[i] - m) * inv * s[j] + b[j];
        out_attn[(long)row * 512 + j] = v[i];
        nrm += v[i] * v[i];
    }
    #pragma unroll
    for (int off = 32; off; off >>= 1) nrm += __shfl_xor(nrm, off);
    const float rinv = rsqrtf(nrm);
    #pragma unroll
    for (int i = 0; i < 8; ++i)
        nb[(long)row * 512 + lane + (i << 6)] = f2bu(v[i] * rinv);
}

// -------- init: x -> MEMf, Yf (fp32) + MEMb, Yb (bf16) -----------------------
__global__ __launch_bounds__(256)
void init_k(const float* __restrict__ x, float* __restrict__ mf, float* __restrict__ yf,
            unsigned short* __restrict__ mb, unsigned short* __restrict__ yb)
{
    const long i = ((long)blockIdx.x * 256 + threadIdx.x) * 4;
    const float4 v = *(const float4*)(x + i);
    *(float4*)(mf + i) = v;
    *(float4*)(yf + i) = v;
    short4v s;
    s[0] = (short)f2bu(v.x); s[1] = (short)f2bu(v.y);
    s[2] = (short)f2bu(v.z); s[3] = (short)f2bu(v.w);
    *(short4v*)(mb + i) = s;
    *(short4v*)(yb + i) = s;
}

// ------------------------------ host side ------------------------------------
static void gemm4(hipStream_t st, bool relu, bool obf16,
                  const unsigned short* A, int lda, long sA,
                  const unsigned short* B, int ldb, long sB,
                  const float* bias, void* C, int ldc, long sC,
                  int M, int N, int K, float alpha, int batch,
                  unsigned short* VTp = nullptr, int vt_col0 = 0,
                  const unsigned short* A2 = nullptr, int a2_col = 0,
                  int kz = 0)
{
    dim3 g(N / 64, M / 64, batch);
    if (obf16) {
        if (relu) gemm4_k<true,  true ><<<g, 256, 0, st>>>(A, A2, a2_col, lda, sA, B, ldb, sB, bias, C, ldc, sC, K, alpha, VTp, vt_col0, kz);
        else      gemm4_k<false, true ><<<g, 256, 0, st>>>(A, A2, a2_col, lda, sA, B, ldb, sB, bias, C, ldc, sC, K, alpha, VTp, vt_col0, kz);
    } else {
        if (relu) gemm4_k<true,  false><<<g, 256, 0, st>>>(A, A2, a2_col, lda, sA, B, ldb, sB, bias, C, ldc, sC, K, alpha, VTp, vt_col0, kz);
        else      gemm4_k<false, false><<<g, 256, 0, st>>>(A, A2, a2_col, lda, sA, B, ldb, sB, bias, C, ldc, sC, K, alpha, VTp, vt_col0, kz);
    }
}

extern "C" void kernel_launch(void* const* d_in, const int* in_sizes, int n_in,
                              void* d_out, int out_size, void* d_ws, size_t ws_size,
                              hipStream_t stream)
{
    const float* x            = (const float*)d_in[0];
    const float* enc_qkv_w    = (const float*)d_in[1];
    const float* enc_qkv_b    = (const float*)d_in[2];
    const float* enc_out_w    = (const float*)d_in[3];
    const float* enc_out_b    = (const float*)d_in[4];
    const float* enc_ff1_w    = (const float*)d_in[5];
    const float* enc_ff1_b    = (const float*)d_in[6];
    const float* enc_ff2_w    = (const float*)d_in[7];
    const float* enc_ff2_b    = (const float*)d_in[8];
    const float* enc_ln1_s    = (const float*)d_in[9];
    const float* enc_ln1_b    = (const float*)d_in[10];
    const float* enc_ln2_s    = (const float*)d_in[11];
    const float* enc_ln2_b    = (const float*)d_in[12];
    const float* dec_sa_qkv_w = (const float*)d_in[13];
    const float* dec_sa_qkv_b = (const float*)d_in[14];
    const float* dec_sa_out_w = (const float*)d_in[15];
    const float* dec_sa_out_b = (const float*)d_in[16];
    const float* dec_ca_qkv_w = (const float*)d_in[17];
    const float* dec_ca_qkv_b = (const float*)d_in[18];
    const float* dec_ca_out_w = (const float*)d_in[19];
    const float* dec_ca_out_b = (const float*)d_in[20];
    const float* dec_ff1_w    = (const float*)d_in[21];
    const float* dec_ff1_b    = (const float*)d_in[22];
    const float* dec_ff2_w    = (const float*)d_in[23];
    const float* dec_ff2_b    = (const float*)d_in[24];
    const float* dec_ln1_s    = (const float*)d_in[25];
    const float* dec_ln1_b    = (const float*)d_in[26];
    const float* dec_ln2_s    = (const float*)d_in[27];
    const float* dec_ln2_b    = (const float*)d_in[28];
    const float* dec_ln3_s    = (const float*)d_in[29];
    const float* dec_ln3_b    = (const float*)d_in[30];
    const float* enc_norm_s   = (const float*)d_in[31];
    const float* enc_norm_b   = (const float*)d_in[32];
    const float* dec_norm_s   = (const float*)d_in[33];
    const float* dec_norm_b   = (const float*)d_in[34];

    char* p = (char*)d_ws;
    auto alloc = [&](size_t bytes) -> char* {
        char* r = p; p += (bytes + 255) & ~(size_t)255; return r;
    };
    float*          MEMf = (float*)alloc(1024 * 512 * 4);
    float*          Yf   = (float*)alloc(1024 * 512 * 4);
    unsigned short* MEMb = (unsigned short*)alloc(1024 * 512 * 2);
    unsigned short* Yb   = (unsigned short*)alloc(1024 * 512 * 2);
    unsigned short* QKVb = (unsigned short*)alloc(1024 * 1536 * 2);
    unsigned short* VT   = (unsigned short*)alloc(8L * 64 * 1024 * 2);
    unsigned short* AOb  = (unsigned short*)alloc(1024 * 512 * 2);
    float*          SLAB = (float*)alloc(4L * 1024 * 512 * 4);   // 4 fp32 slabs
    unsigned short* F1b  = (unsigned short*)alloc(1024L * 2048 * 2);
    unsigned short* NBb  = (unsigned short*)alloc(1024 * 512 * 2);

    const float* wsrc[10] = {enc_qkv_w, enc_out_w, enc_ff1_w, enc_ff2_w,
                             dec_sa_qkv_w, dec_sa_out_w, dec_ca_qkv_w, dec_ca_out_w,
                             dec_ff1_w, dec_ff2_w};
    const long wper[10] = {1536L*512, 512L*512, 2048L*512, 512L*2048,
                           1536L*512, 512L*512, 1536L*512, 512L*512,
                           2048L*512, 512L*2048};
    long wtot = 0;
    for (int t = 0; t < 10; ++t) wtot += wper[t] * NLAY;

    const size_t used = (size_t)(p - (char*)d_ws);
    const bool preconv = (ws_size > used) && ((ws_size - used) >= (size_t)wtot * 2 + 4096);

    unsigned short* wpre[10] = {};
    unsigned short* slots[2] = {};
    int slot_ctr = 0;
    if (preconv) {
        WCvt wc;
        wc.cum[0] = 0;
        for (int t = 0; t < 10; ++t) {
            wpre[t] = (unsigned short*)alloc((size_t)wper[t] * NLAY * 2);
            wc.src[t] = wsrc[t];
            wc.dst[t] = wpre[t];
            wc.cum[t + 1] = wc.cum[t] + wper[t] * NLAY / 8;
        }
        f2ball_k<<<dim3(2048), 256, 0, stream>>>(wc);
    } else {
        slots[0] = (unsigned short*)alloc(2048L * 512 * 2);
        slots[1] = (unsigned short*)alloc(2048L * 512 * 2);
    }
    auto W = [&](int t, int layer) -> const unsigned short* {
        if (preconv) return wpre[t] + (long)layer * wper[t];
        unsigned short* dst = slots[(slot_ctr++) & 1];
        const long n = wper[t];
        long blocks = (n / 8 + 255) / 256; if (blocks > 2048) blocks = 2048;
        f2b_k<<<dim3((unsigned)blocks), 256, 0, stream>>>(wsrc[t] + (long)layer * wper[t], dst, n);
        return dst;
    };

    float* out_gram = (float*)d_out;
    float* out_attn = out_gram + 1024 * 1024;

    // attention block: merged QKV GEMM -> fused attn -> proj split-K(2) slabs
    auto run_attn = [&](const unsigned short* qb, const unsigned short* kvb,
                        int wt_qkv, int wt_o, int layer, const float* bqkv) {
        gemm4(stream, false, true, qb, 512, 0, W(wt_qkv, layer), 512, 0, bqkv,
              QKVb, 1536, 0, 1024, 1536, 512, 1.0f, 1, VT, 1024,
              (qb == kvb) ? nullptr : kvb, 512);
        attn_k<<<dim3(32, 8), 128, 0, stream>>>(QKVb, VT, AOb);
        gemm4(stream, false, false, AOb, 512, 0, W(wt_o, layer), 512, 0, nullptr,
              SLAB, 512, 524288, 1024, 512, 256, 1.0f, 2,
              nullptr, 0, nullptr, 0, 256);   // split-K x2 -> 2 slabs
    };
    // FFN: FF1 (relu, bf16) -> FF2 split-K(4) slabs
    auto run_ffn = [&](const unsigned short* inb, int wt1, int wt2, int layer,
                       const float* b1) {
        gemm4(stream, true, true, inb, 512, 0, W(wt1, layer), 512, 0, b1,
              F1b, 2048, 0, 1024, 2048, 512, 1.0f, 1);
        gemm4(stream, false, false, F1b, 2048, 0, W(wt2, layer), 2048, 0, nullptr,
              SLAB, 512, 524288, 1024, 512, 512, 1.0f, 4,
              nullptr, 0, nullptr, 0, 512);   // split-K x4 -> 4 slabs
    };

    init_k<<<512, 256, 0, stream>>>(x, MEMf, Yf, MEMb, Yb);

    // ----------------------------- encoder -----------------------------------
    for (int i = 0; i < NLAY; ++i) {
        run_attn(MEMb, MEMb, 0, 1, i, enc_qkv_b + i * 1536);
        ln_k<<<256, 256, 0, stream>>>(MEMf, SLAB, 2, enc_out_b + i * 512,
                                      enc_ln1_s + i * 512, enc_ln1_b + i * 512, MEMf, MEMb);
        run_ffn(MEMb, 2, 3, i, enc_ff1_b + i * 2048);
        ln_k<<<256, 256, 0, stream>>>(MEMf, SLAB, 4, enc_ff2_b + i * 512,
                                      enc_ln2_s + i * 512, enc_ln2_b + i * 512, MEMf, MEMb);
    }
    ln_k<<<256, 256, 0, stream>>>(MEMf, nullptr, 0, nullptr, enc_norm_s, enc_norm_b, MEMf, MEMb);

    // ----------------------------- decoder -----------------------------------
    for (int i = 0; i < NLAY; ++i) {
        run_attn(Yb, Yb, 4, 5, i, dec_sa_qkv_b + i * 1536);
        ln_k<<<256, 256, 0, stream>>>(Yf, SLAB, 2, dec_sa_out_b + i * 512,
                                      dec_ln1_s + i * 512, dec_ln1_b + i * 512, Yf, Yb);

        run_attn(Yb, MEMb, 6, 7, i, dec_ca_qkv_b + i * 1536);
        ln_k<<<256, 256, 0, stream>>>(Yf, SLAB, 2, dec_ca_out_b + i * 512,
                                      dec_ln2_s + i * 512, dec_ln2_b + i * 512, Yf, Yb);

        run_ffn(Yb, 8, 9, i, dec_ff1_b + i * 2048);
        ln_k<<<256, 256, 0, stream>>>(Yf, SLAB, 4, dec_ff2_b + i * 512,
                                      dec_ln3_s + i * 512, dec_ln3_b + i * 512, Yf, Yb);
    }

    // final: attention_out + n = rownorm (fused), gram = n@n^T
    lnl2_k<<<256, 256, 0, stream>>>(Yf, dec_norm_s, dec_norm_b, out_attn, NBb);
    gemm4(stream, false, false, NBb, 512, 0, NBb, 512, 0, nullptr,
          out_gram, 1024, 0, 1024, 1024, 512, 1.0f, 1);
}

// Round 6
// 1447.187 us; speedup vs baseline: 4.6401x; 1.0122x over previous
//
#include <hip/hip_runtime.h>

// MyTransformer: 6-enc + 6-dec, S=1024, D=512, H=8x64, FF=2048.
// Round 5: f2ball 32 elem/thread (8-wide MLP); GEMM 5-buffer depth-4 pipeline
// (vmcnt(12) steady); split-K slabs + LN-merge; fused flash attention.

#define NLAY 6

typedef __attribute__((ext_vector_type(8))) short short8;
typedef __attribute__((ext_vector_type(4))) short short4v;
typedef __attribute__((ext_vector_type(4))) float f32x4;

typedef __attribute__((address_space(3))) short lds_short;
typedef __attribute__((address_space(1))) const unsigned short g_ushort;

__device__ __forceinline__ void gload16(const unsigned short* g, short* l) {
    __builtin_amdgcn_global_load_lds((g_ushort*)g, (lds_short*)l, 16, 0, 0);
}

__device__ __forceinline__ void waitvm(int n) {   // wave-uniform literal waits
    if (n == 0)      asm volatile("s_waitcnt vmcnt(0)" ::: "memory");
    else if (n == 4) asm volatile("s_waitcnt vmcnt(4)" ::: "memory");
    else if (n == 8) asm volatile("s_waitcnt vmcnt(8)" ::: "memory");
    else             asm volatile("s_waitcnt vmcnt(12)" ::: "memory");
}

__device__ inline unsigned short f2bu(float x) {
    unsigned u = __builtin_bit_cast(unsigned, x);
    unsigned r = (u + 0x7fffu + ((u >> 16) & 1u)) >> 16;   // RNE
    return (unsigned short)r;
}

// ------------- fp32 -> bf16 weight cvt: 32 elems/thread, 8-wide MLP ----------
struct WCvt {
    const float* src[10];
    unsigned short* dst[10];
    long cum[11];           // prefix sums in 32-element chunks
};

__global__ __launch_bounds__(256)
void f2ball_k(WCvt wc)
{
    const long total = wc.cum[10];
    for (long c = (long)blockIdx.x * 256 + threadIdx.x; c < total;
         c += (long)gridDim.x * 256) {
        int t = 0;
        #pragma unroll
        for (int i = 1; i < 10; ++i) if (c >= wc.cum[i]) t = i;
        const long o = (c - wc.cum[t]) * 32;
        const float* s = wc.src[t] + o;
        unsigned short* d = wc.dst[t] + o;
        float4 a[8];
        #pragma unroll
        for (int i = 0; i < 8; ++i) a[i] = *(const float4*)(s + i * 4);
        #pragma unroll
        for (int i = 0; i < 4; ++i) {
            short8 v;
            v[0] = (short)f2bu(a[2 * i].x);     v[1] = (short)f2bu(a[2 * i].y);
            v[2] = (short)f2bu(a[2 * i].z);     v[3] = (short)f2bu(a[2 * i].w);
            v[4] = (short)f2bu(a[2 * i + 1].x); v[5] = (short)f2bu(a[2 * i + 1].y);
            v[6] = (short)f2bu(a[2 * i + 1].z); v[7] = (short)f2bu(a[2 * i + 1].w);
            *(short8*)(d + i * 8) = v;
        }
    }
}

__global__ __launch_bounds__(256)
void f2b_k(const float* __restrict__ s, unsigned short* __restrict__ d, long n)
{
    const long stride = (long)gridDim.x * 256;
    for (long i = (long)blockIdx.x * 256 + threadIdx.x; i * 8 < n; i += stride) {
        const long o = i * 8;
        const float4 a = *(const float4*)(s + o);
        const float4 b = *(const float4*)(s + o + 4);
        short8 v;
        v[0] = (short)f2bu(a.x); v[1] = (short)f2bu(a.y);
        v[2] = (short)f2bu(a.z); v[3] = (short)f2bu(a.w);
        v[4] = (short)f2bu(b.x); v[5] = (short)f2bu(b.y);
        v[6] = (short)f2bu(b.z); v[7] = (short)f2bu(b.w);
        *(short8*)(d + o) = v;
    }
}

// ---------------- 4-wave MFMA GEMM: C = alpha * A @ B^T + bias ---------------
// A: [M][K] bf16 (lda), B: [N][K] bf16 (ldb). 256 thr = 4 waves, tile 64x64,
// wave w owns rows [w*16, w*16+16). BK=64, 5-buffer LDS pipeline via
// global_load_lds, prefetch depth 4, vmcnt(12) steady. Per-z: A/B element
// offset += z*kz (split-K), C += z*sC (slab). If A2: blocks with n0 >= a2_col
// read A2. If VTp: cols n >= vt_col0 also scatter to VTp[h][d][m] (bf16).
template<bool RELU, bool OBF16>
__global__ __launch_bounds__(256)
void gemm5_k(const unsigned short* __restrict__ A,
             const unsigned short* __restrict__ A2, int a2_col,
             int lda, long sA,
             const unsigned short* __restrict__ B, int ldb, long sB,
             const float* __restrict__ bias,
             void* __restrict__ Cv, int ldc, long sC,
             int K, float alpha,
             unsigned short* __restrict__ VTp, int vt_col0, int kz)
{
    __shared__ __align__(16) short As[5][64 * 64];   // 40 KB
    __shared__ __align__(16) short Bs[5][64 * 64];   // 40 KB
    const int bz = blockIdx.z;
    const int m0 = blockIdx.y * 64;
    const int n0 = blockIdx.x * 64;
    if (A2 && n0 >= a2_col) A = A2;
    A += (long)bz * sA + (long)bz * kz;
    B += (long)bz * sB + (long)bz * kz;
    const int tid = threadIdx.x;
    const int w  = tid >> 6;
    const int l  = tid & 63;
    const int fr = l & 15;
    const int kc = l >> 4;

    f32x4 acc[4] = {};
    const int T = K >> 6;

    auto FILL = [&](int t, int buf) {
        const int k0 = t * 64;
        #pragma unroll
        for (int it = 0; it < 2; ++it) {
            const int row = w * 16 + it * 8 + (l >> 3);
            const int sl  = ((l & 7) ^ (row & 7)) * 8;
            gload16(A + (long)(m0 + row) * lda + k0 + sl, &As[buf][(w * 16 + it * 8) * 64]);
            gload16(B + (long)(n0 + row) * ldb + k0 + sl, &Bs[buf][(w * 16 + it * 8) * 64]);
        }
    };

    FILL(0, 0);
    if (T > 1) FILL(1, 1);
    if (T > 2) FILL(2, 2);
    if (T > 3) FILL(3, 3);
    int cb = 0, fb = 4;
    for (int t = 0; t < T; ++t) {
        const int rem = T - 1 - t;
        waitvm(rem >= 3 ? 12 : rem * 4);
        __builtin_amdgcn_sched_barrier(0);
        __builtin_amdgcn_s_barrier();
        if (t + 4 < T) FILL(t + 4, fb);
        fb = (fb == 4) ? 0 : fb + 1;
        #pragma unroll
        for (int ks = 0; ks < 2; ++ks) {
            const int arow = w * 16 + fr;
            const short8 af = *(const short8*)&As[cb][arow * 64 + (((ks * 4 + kc) ^ (arow & 7)) * 8)];
            #pragma unroll
            for (int c = 0; c < 4; ++c) {
                const int brow = c * 16 + fr;
                const short8 bf = *(const short8*)&Bs[cb][brow * 64 + (((ks * 4 + kc) ^ (brow & 7)) * 8)];
                acc[c] = __builtin_amdgcn_mfma_f32_16x16x32_bf16(af, bf, acc[c], 0, 0, 0);
            }
        }
        cb = (cb == 4) ? 0 : cb + 1;
    }

    #pragma unroll
    for (int c = 0; c < 4; ++c) {
        const int n = n0 + c * 16 + fr;
        const float bv = bias ? bias[n] : 0.0f;
        const bool do_vt = (VTp != nullptr) && (n >= vt_col0);
        #pragma unroll
        for (int i = 0; i < 4; ++i) {
            const long m = m0 + w * 16 + kc * 4 + i;
            float v = acc[c][i] * alpha + bv;
            if (RELU) v = fmaxf(v, 0.0f);
            if (OBF16) ((unsigned short*)Cv)[bz * sC + m * ldc + n] = f2bu(v);
            else       ((float*)Cv)[bz * sC + m * ldc + n] = v;
            if (do_vt) {
                const int vc = n - vt_col0;
                VTp[(long)(vc >> 6) * 65536 + (long)(vc & 63) * 1024 + m] = f2bu(v);
            }
        }
    }
}

// ---------------- fused attention: O = softmax(QK^T/8) V ---------------------
// Grid (32 q-tiles of 32 rows, 8 heads), 128 thr = 2 waves; wave w owns q rows
// qt*32+w*16..+16. Q in regs; K (QKVb) and V (VT=[h][d][s]) in a 3-buffer
// LDS pipeline; online softmax in-register; P via wave-private swizzled LDS.
__global__ __launch_bounds__(128)
void attn_k(const unsigned short* __restrict__ QKVb,   // [1024][1536]
            const unsigned short* __restrict__ VT,     // [8][64][1024]
            unsigned short* __restrict__ AOb)          // [1024][512]
{
    __shared__ __align__(16) short Ks[3][64 * 64];     // 24 KB
    __shared__ __align__(16) short Vs[3][64 * 64];     // 24 KB
    __shared__ __align__(16) short Ps[2][16 * 64];     // 4 KB
    const int qt = blockIdx.x;
    const int h  = blockIdx.y;
    const int tid = threadIdx.x;
    const int w  = tid >> 6;      // 0..1
    const int l  = tid & 63;
    const int fr = l & 15;
    const int kc = l >> 4;

    const int qrow = qt * 32 + w * 16 + fr;
    short8 qf[2];
    qf[0] = *(const short8*)(QKVb + (long)qrow * 1536 + h * 64 + kc * 8);
    qf[1] = *(const short8*)(QKVb + (long)qrow * 1536 + h * 64 + 32 + kc * 8);

    auto FILL = [&](int t, int buf) {
        const int kb = t * 64;
        #pragma unroll
        for (int it = 0; it < 4; ++it) {
            const int row = it * 16 + w * 8 + (l >> 3);
            const int sl  = ((l & 7) ^ (row & 7)) * 8;
            gload16(QKVb + (long)(kb + row) * 1536 + 512 + h * 64 + sl,
                    &Ks[buf][(it * 16 + w * 8) * 64]);
            gload16(VT + (long)h * 65536 + (long)row * 1024 + kb + sl,
                    &Vs[buf][(it * 16 + w * 8) * 64]);
        }
    };

    float m_i[4], l_i[4];
    f32x4 acc_o[4] = {};
    #pragma unroll
    for (int i = 0; i < 4; ++i) { m_i[i] = -1e30f; l_i[i] = 0.f; }

    short* ps = &Ps[w][0];

    FILL(0, 0); FILL(1, 1);
    int fb = 2, cb = 0;
    for (int t = 0; t < 16; ++t) {
        waitvm(t == 15 ? 0 : 8);
        __builtin_amdgcn_sched_barrier(0);
        __builtin_amdgcn_s_barrier();
        if (t + 2 < 16) { FILL(t + 2, fb); fb = (fb == 2) ? 0 : fb + 1; }

        // S = Q @ K^T
        f32x4 sacc[4] = {};
        #pragma unroll
        for (int ks = 0; ks < 2; ++ks) {
            #pragma unroll
            for (int c = 0; c < 4; ++c) {
                const int krow = c * 16 + fr;
                const short8 kf = *(const short8*)&Ks[cb][krow * 64 + (((ks * 4 + kc) ^ (krow & 7)) * 8)];
                sacc[c] = __builtin_amdgcn_mfma_f32_16x16x32_bf16(qf[ks], kf, sacc[c], 0, 0, 0);
            }
        }

        // online softmax (scale 1/8); rows lane-local per 16-lane group
        float p[4][4];
        #pragma unroll
        for (int i = 0; i < 4; ++i) {
            float tm = fmaxf(fmaxf(sacc[0][i], sacc[1][i]), fmaxf(sacc[2][i], sacc[3][i]));
            #pragma unroll
            for (int off = 8; off; off >>= 1) tm = fmaxf(tm, __shfl_xor(tm, off));
            tm *= 0.125f;
            const float mn = fmaxf(m_i[i], tm);
            const float sc = __expf(m_i[i] - mn);
            m_i[i] = mn;
            float ts = 0.f;
            #pragma unroll
            for (int c = 0; c < 4; ++c) { p[c][i] = __expf(sacc[c][i] * 0.125f - mn); ts += p[c][i]; }
            #pragma unroll
            for (int off = 8; off; off >>= 1) ts += __shfl_xor(ts, off);
            l_i[i] = l_i[i] * sc + ts;
            #pragma unroll
            for (int c = 0; c < 4; ++c) acc_o[c][i] *= sc;
        }

        // P -> wave-private LDS (bf16, swizzled at 8-elem granularity)
        #pragma unroll
        for (int c = 0; c < 4; ++c) {
            const int col = c * 16 + fr;
            #pragma unroll
            for (int i = 0; i < 4; ++i) {
                const int row = kc * 4 + i;
                ps[row * 64 + (((col >> 3) ^ (row & 7)) * 8) + (col & 7)] = (short)f2bu(p[c][i]);
            }
        }
        short8 pf[2];
        pf[0] = *(const short8*)&ps[fr * 64 + ((kc ^ (fr & 7)) * 8)];
        pf[1] = *(const short8*)&ps[fr * 64 + (((4 + kc) ^ (fr & 7)) * 8)];

        // O += P @ V
        #pragma unroll
        for (int ks = 0; ks < 2; ++ks) {
            #pragma unroll
            for (int c = 0; c < 4; ++c) {
                const int drow = c * 16 + fr;
                const short8 vf = *(const short8*)&Vs[cb][drow * 64 + (((ks * 4 + kc) ^ (drow & 7)) * 8)];
                acc_o[c] = __builtin_amdgcn_mfma_f32_16x16x32_bf16(pf[ks], vf, acc_o[c], 0, 0, 0);
            }
        }
        cb = (cb == 2) ? 0 : cb + 1;
    }

    #pragma unroll
    for (int c = 0; c < 4; ++c) {
        const int dcol = h * 64 + c * 16 + fr;
        #pragma unroll
        for (int i = 0; i < 4; ++i) {
            const int row = qt * 32 + w * 16 + kc * 4 + i;
            AOb[(long)row * 512 + dcol] = f2bu(acc_o[c][i] / l_i[i]);
        }
    }
}

// -------- LayerNorm-as-merge: out = LN(x + sum_slabs + bias)*s + b -----------
__global__ __launch_bounds__(256)
void ln_k(const float* __restrict__ x, const float* __restrict__ slab, int nslab,
          const float* __restrict__ bias,
          const float* __restrict__ s, const float* __restrict__ b,
          float* __restrict__ out, unsigned short* __restrict__ outb)
{
    const int lane = threadIdx.x & 63;
    const int row  = (blockIdx.x << 2) + (threadIdx.x >> 6);
    const float* px = x + (long)row * 512;
    float v[8];
    float sum = 0.f;
    #pragma unroll
    for (int i = 0; i < 8; ++i) {
        const int j = lane + (i << 6);
        v[i] = px[j];
        for (int t = 0; t < nslab; ++t) v[i] += slab[(long)t * 524288 + (long)row * 512 + j];
        if (bias) v[i] += bias[j];
        sum += v[i];
    }
    #pragma unroll
    for (int off = 32; off; off >>= 1) sum += __shfl_xor(sum, off);
    const float m = sum * (1.0f / 512.0f);
    float s2 = 0.f;
    #pragma unroll
    for (int i = 0; i < 8; ++i) { const float d = v[i] - m; s2 += d * d; }
    #pragma unroll
    for (int off = 32; off; off >>= 1) s2 += __shfl_xor(s2, off);
    const float inv = rsqrtf(s2 * (1.0f / 512.0f) + 1e-5f);
    #pragma unroll
    for (int i = 0; i < 8; ++i) {
        const int j = lane + (i << 6);
        const float r = (v[i] - m) * inv * s[j] + b[j];
        out[(long)row * 512 + j] = r;
        if (outb) outb[(long)row * 512 + j] = f2bu(r);
    }
}

// -------- fused final LN + L2-normalize --------------------------------------
__global__ __launch_bounds__(256)
void lnl2_k(const float* __restrict__ x,
            const float* __restrict__ s, const float* __restrict__ b,
            float* __restrict__ out_attn, unsigned short* __restrict__ nb)
{
    const int lane = threadIdx.x & 63;
    const int row  = (blockIdx.x << 2) + (threadIdx.x >> 6);
    const float* px = x + (long)row * 512;
    float v[8];
    float sum = 0.f;
    #pragma unroll
    for (int i = 0; i < 8; ++i) { v[i] = px[lane + (i << 6)]; sum += v[i]; }
    #pragma unroll
    for (int off = 32; off; off >>= 1) sum += __shfl_xor(sum, off);
    const float m = sum * (1.0f / 512.0f);
    float s2 = 0.f;
    #pragma unroll
    for (int i = 0; i < 8; ++i) { const float d = v[i] - m; s2 += d * d; }
    #pragma unroll
    for (int off = 32; off; off >>= 1) s2 += __shfl_xor(s2, off);
    const float inv = rsqrtf(s2 * (1.0f / 512.0f) + 1e-5f);
    float nrm = 0.f;
    #pragma unroll
    for (int i = 0; i < 8; ++i) {
        const int j = lane + (i << 6);
        v[i] = (v[i] - m) * inv * s[j] + b[j];
        out_attn[(long)row * 512 + j] = v[i];
        nrm += v[i] * v[i];
    }
    #pragma unroll
    for (int off = 32; off; off >>= 1) nrm += __shfl_xor(nrm, off);
    const float rinv = rsqrtf(nrm);
    #pragma unroll
    for (int i = 0; i < 8; ++i)
        nb[(long)row * 512 + lane + (i << 6)] = f2bu(v[i] * rinv);
}

// -------- init: x -> MEMf, Yf (fp32) + MEMb, Yb (bf16) -----------------------
__global__ __launch_bounds__(256)
void init_k(const float* __restrict__ x, float* __restrict__ mf, float* __restrict__ yf,
            unsigned short* __restrict__ mb, unsigned short* __restrict__ yb)
{
    const long i = ((long)blockIdx.x * 256 + threadIdx.x) * 4;
    const float4 v = *(const float4*)(x + i);
    *(float4*)(mf + i) = v;
    *(float4*)(yf + i) = v;
    short4v s;
    s[0] = (short)f2bu(v.x); s[1] = (short)f2bu(v.y);
    s[2] = (short)f2bu(v.z); s[3] = (short)f2bu(v.w);
    *(short4v*)(mb + i) = s;
    *(short4v*)(yb + i) = s;
}

// ------------------------------ host side ------------------------------------
static void gemm5(hipStream_t st, bool relu, bool obf16,
                  const unsigned short* A, int lda, long sA,
                  const unsigned short* B, int ldb, long sB,
                  const float* bias, void* C, int ldc, long sC,
                  int M, int N, int K, float alpha, int batch,
                  unsigned short* VTp = nullptr, int vt_col0 = 0,
                  const unsigned short* A2 = nullptr, int a2_col = 0,
                  int kz = 0)
{
    dim3 g(N / 64, M / 64, batch);
    if (obf16) {
        if (relu) gemm5_k<true,  true ><<<g, 256, 0, st>>>(A, A2, a2_col, lda, sA, B, ldb, sB, bias, C, ldc, sC, K, alpha, VTp, vt_col0, kz);
        else      gemm5_k<false, true ><<<g, 256, 0, st>>>(A, A2, a2_col, lda, sA, B, ldb, sB, bias, C, ldc, sC, K, alpha, VTp, vt_col0, kz);
    } else {
        if (relu) gemm5_k<true,  false><<<g, 256, 0, st>>>(A, A2, a2_col, lda, sA, B, ldb, sB, bias, C, ldc, sC, K, alpha, VTp, vt_col0, kz);
        else      gemm5_k<false, false><<<g, 256, 0, st>>>(A, A2, a2_col, lda, sA, B, ldb, sB, bias, C, ldc, sC, K, alpha, VTp, vt_col0, kz);
    }
}

extern "C" void kernel_launch(void* const* d_in, const int* in_sizes, int n_in,
                              void* d_out, int out_size, void* d_ws, size_t ws_size,
                              hipStream_t stream)
{
    const float* x            = (const float*)d_in[0];
    const float* enc_qkv_w    = (const float*)d_in[1];
    const float* enc_qkv_b    = (const float*)d_in[2];
    const float* enc_out_w    = (const float*)d_in[3];
    const float* enc_out_b    = (const float*)d_in[4];
    const float* enc_ff1_w    = (const float*)d_in[5];
    const float* enc_ff1_b    = (const float*)d_in[6];
    const float* enc_ff2_w    = (const float*)d_in[7];
    const float* enc_ff2_b    = (const float*)d_in[8];
    const float* enc_ln1_s    = (const float*)d_in[9];
    const float* enc_ln1_b    = (const float*)d_in[10];
    const float* enc_ln2_s    = (const float*)d_in[11];
    const float* enc_ln2_b    = (const float*)d_in[12];
    const float* dec_sa_qkv_w = (const float*)d_in[13];
    const float* dec_sa_qkv_b = (const float*)d_in[14];
    const float* dec_sa_out_w = (const float*)d_in[15];
    const float* dec_sa_out_b = (const float*)d_in[16];
    const float* dec_ca_qkv_w = (const float*)d_in[17];
    const float* dec_ca_qkv_b = (const float*)d_in[18];
    const float* dec_ca_out_w = (const float*)d_in[19];
    const float* dec_ca_out_b = (const float*)d_in[20];
    const float* dec_ff1_w    = (const float*)d_in[21];
    const float* dec_ff1_b    = (const float*)d_in[22];
    const float* dec_ff2_w    = (const float*)d_in[23];
    const float* dec_ff2_b    = (const float*)d_in[24];
    const float* dec_ln1_s    = (const float*)d_in[25];
    const float* dec_ln1_b    = (const float*)d_in[26];
    const float* dec_ln2_s    = (const float*)d_in[27];
    const float* dec_ln2_b    = (const float*)d_in[28];
    const float* dec_ln3_s    = (const float*)d_in[29];
    const float* dec_ln3_b    = (const float*)d_in[30];
    const float* enc_norm_s   = (const float*)d_in[31];
    const float* enc_norm_b   = (const float*)d_in[32];
    const float* dec_norm_s   = (const float*)d_in[33];
    const float* dec_norm_b   = (const float*)d_in[34];

    char* p = (char*)d_ws;
    auto alloc = [&](size_t bytes) -> char* {
        char* r = p; p += (bytes + 255) & ~(size_t)255; return r;
    };
    float*          MEMf = (float*)alloc(1024 * 512 * 4);
    float*          Yf   = (float*)alloc(1024 * 512 * 4);
    unsigned short* MEMb = (unsigned short*)alloc(1024 * 512 * 2);
    unsigned short* Yb   = (unsigned short*)alloc(1024 * 512 * 2);
    unsigned short* QKVb = (unsigned short*)alloc(1024 * 1536 * 2);
    unsigned short* VT   = (unsigned short*)alloc(8L * 64 * 1024 * 2);
    unsigned short* AOb  = (unsigned short*)alloc(1024 * 512 * 2);
    float*          SLAB = (float*)alloc(4L * 1024 * 512 * 4);   // 4 fp32 slabs
    unsigned short* F1b  = (unsigned short*)alloc(1024L * 2048 * 2);
    unsigned short* NBb  = (unsigned short*)alloc(1024 * 512 * 2);

    const float* wsrc[10] = {enc_qkv_w, enc_out_w, enc_ff1_w, enc_ff2_w,
                             dec_sa_qkv_w, dec_sa_out_w, dec_ca_qkv_w, dec_ca_out_w,
                             dec_ff1_w, dec_ff2_w};
    const long wper[10] = {1536L*512, 512L*512, 2048L*512, 512L*2048,
                           1536L*512, 512L*512, 1536L*512, 512L*512,
                           2048L*512, 512L*2048};
    long wtot = 0;
    for (int t = 0; t < 10; ++t) wtot += wper[t] * NLAY;

    const size_t used = (size_t)(p - (char*)d_ws);
    const bool preconv = (ws_size > used) && ((ws_size - used) >= (size_t)wtot * 2 + 4096);

    unsigned short* wpre[10] = {};
    unsigned short* slots[2] = {};
    int slot_ctr = 0;
    if (preconv) {
        WCvt wc;
        wc.cum[0] = 0;
        for (int t = 0; t < 10; ++t) {
            wpre[t] = (unsigned short*)alloc((size_t)wper[t] * NLAY * 2);
            wc.src[t] = wsrc[t];
            wc.dst[t] = wpre[t];
            wc.cum[t + 1] = wc.cum[t] + wper[t] * NLAY / 32;
        }
        f2ball_k<<<dim3(2048), 256, 0, stream>>>(wc);
    } else {
        slots[0] = (unsigned short*)alloc(2048L * 512 * 2);
        slots[1] = (unsigned short*)alloc(2048L * 512 * 2);
    }
    auto W = [&](int t, int layer) -> const unsigned short* {
        if (preconv) return wpre[t] + (long)layer * wper[t];
        unsigned short* dst = slots[(slot_ctr++) & 1];
        const long n = wper[t];
        long blocks = (n / 8 + 255) / 256; if (blocks > 2048) blocks = 2048;
        f2b_k<<<dim3((unsigned)blocks), 256, 0, stream>>>(wsrc[t] + (long)layer * wper[t], dst, n);
        return dst;
    };

    float* out_gram = (float*)d_out;
    float* out_attn = out_gram + 1024 * 1024;

    // attention block: merged QKV GEMM -> fused attn -> proj split-K(2) slabs
    auto run_attn = [&](const unsigned short* qb, const unsigned short* kvb,
                        int wt_qkv, int wt_o, int layer, const float* bqkv) {
        gemm5(stream, false, true, qb, 512, 0, W(wt_qkv, layer), 512, 0, bqkv,
              QKVb, 1536, 0, 1024, 1536, 512, 1.0f, 1, VT, 1024,
              (qb == kvb) ? nullptr : kvb, 512);
        attn_k<<<dim3(32, 8), 128, 0, stream>>>(QKVb, VT, AOb);
        gemm5(stream, false, false, AOb, 512, 0, W(wt_o, layer), 512, 0, nullptr,
              SLAB, 512, 524288, 1024, 512, 256, 1.0f, 2,
              nullptr, 0, nullptr, 0, 256);   // split-K x2 -> 2 slabs
    };
    // FFN: FF1 (relu, bf16) -> FF2 split-K(4) slabs
    auto run_ffn = [&](const unsigned short* inb, int wt1, int wt2, int layer,
                       const float* b1) {
        gemm5(stream, true, true, inb, 512, 0, W(wt1, layer), 512, 0, b1,
              F1b, 2048, 0, 1024, 2048, 512, 1.0f, 1);
        gemm5(stream, false, false, F1b, 2048, 0, W(wt2, layer), 2048, 0, nullptr,
              SLAB, 512, 524288, 1024, 512, 512, 1.0f, 4,
              nullptr, 0, nullptr, 0, 512);   // split-K x4 -> 4 slabs
    };

    init_k<<<512, 256, 0, stream>>>(x, MEMf, Yf, MEMb, Yb);

    // ----------------------------- encoder -----------------------------------
    for (int i = 0; i < NLAY; ++i) {
        run_attn(MEMb, MEMb, 0, 1, i, enc_qkv_b + i * 1536);
        ln_k<<<256, 256, 0, stream>>>(MEMf, SLAB, 2, enc_out_b + i * 512,
                                      enc_ln1_s + i * 512, enc_ln1_b + i * 512, MEMf, MEMb);
        run_ffn(MEMb, 2, 3, i, enc_ff1_b + i * 2048);
        ln_k<<<256, 256, 0, stream>>>(MEMf, SLAB, 4, enc_ff2_b + i * 512,
                                      enc_ln2_s + i * 512, enc_ln2_b + i * 512, MEMf, MEMb);
    }
    ln_k<<<256, 256, 0, stream>>>(MEMf, nullptr, 0, nullptr, enc_norm_s, enc_norm_b, MEMf, MEMb);

    // ----------------------------- decoder -----------------------------------
    for (int i = 0; i < NLAY; ++i) {
        run_attn(Yb, Yb, 4, 5, i, dec_sa_qkv_b + i * 1536);
        ln_k<<<256, 256, 0, stream>>>(Yf, SLAB, 2, dec_sa_out_b + i * 512,
                                      dec_ln1_s + i * 512, dec_ln1_b + i * 512, Yf, Yb);

        run_attn(Yb, MEMb, 6, 7, i, dec_ca_qkv_b + i * 1536);
        ln_k<<<256, 256, 0, stream>>>(Yf, SLAB, 2, dec_ca_out_b + i * 512,
                                      dec_ln2_s + i * 512, dec_ln2_b + i * 512, Yf, Yb);

        run_ffn(Yb, 8, 9, i, dec_ff1_b + i * 2048);
        ln_k<<<256, 256, 0, stream>>>(Yf, SLAB, 4, dec_ff2_b + i * 512,
                                      dec_ln3_s + i * 512, dec_ln3_b + i * 512, Yf, Yb);
    }

    // final: attention_out + n = rownorm (fused), gram = n@n^T
    lnl2_k<<<256, 256, 0, stream>>>(Yf, dec_norm_s, dec_norm_b, out_attn, NBb);
    gemm5(stream, false, false, NBb, 512, 0, NBb, 512, 0, nullptr,
          out_gram, 1024, 0, 1024, 1024, 512, 1.0f, 1);
}